// Round 11
// baseline (795.129 us; speedup 1.0000x reference)
//
#include <hip/hip_runtime.h>
#include <math.h>

#define L_OR 6
#define N_BL 48   // B*L = 8*6

typedef unsigned short u16;
typedef __attribute__((ext_vector_type(8))) short s8v;   // 8 x bf16 (16B)
typedef __attribute__((ext_vector_type(4))) float f4v;

#define N1 196608
#define N2 49152
#define N3 12288
#define LSTRIDE 114688   // u16 stride per layer in g_Bt (96K data + 16K pad)

// ---- static device workspace (BSS, allocated at module load) ----
__device__ u16   g_cat[(size_t)N1 * 768 + 1024];  // 302 MB: 6 T-slots bf16 (+pad)
__device__ u16   g_O[(size_t)N1 * 128];           // 50 MB: GEMM output bf16
__device__ float g_Tt[5 * (size_t)N1 * 3];        // layer-1 T1..T5 fp32
__device__ u16   g_Bt[4 * LSTRIDE];               // fragment-ordered weights, W2..W5
__device__ u16   g_W6t[16 * 768];                 // layer-6 weights (padded cols)
__device__ float g_wt1[(size_t)N1 * 8];           // edge-weight tables per scale
__device__ float g_wt2[(size_t)N2 * 8];
__device__ float g_wt3[(size_t)N3 * 8];
__device__ float g_O10[(size_t)N3 * 10];
__device__ float g_part[1536 * 256];              // per-block BN partials
__device__ float g_part2[64 * 256];               // stage-2 BN partials
__device__ float g_gsc[128];                      // BN combined scale
__device__ float g_gso[128];                      // BN combined offset
__device__ unsigned g_cnt;                        // last-block-done counter

__device__ __forceinline__ float b2f(u16 v) {
    return __uint_as_float(((unsigned)v) << 16);
}
__device__ __forceinline__ u16 f2b(float f) {
    unsigned u = __float_as_uint(f);
    return (u16)((u + 0x7FFFu + ((u >> 16) & 1u)) >> 16);   // RNE
}

// ---------------------------------------------------------------------------
// Edge-weight tables, all three scales in one launch.
// ---------------------------------------------------------------------------
__global__ __launch_bounds__(256)
void eaprep_all(float* __restrict__ wt1, float* __restrict__ wt2,
                float* __restrict__ wt3, const float* __restrict__ ea1,
                const float* __restrict__ ea2, const float* __restrict__ ea3)
{
    int idx = blockIdx.x * 256 + threadIdx.x;
    int S, n; float* wtab; const float* ea;
    if (idx < N1)            { S = 64; wtab = wt1; ea = ea1; n = idx; }
    else if (idx < N1 + N2)  { S = 32; wtab = wt2; ea = ea2; n = idx - N1; }
    else if (idx < N1 + N2 + N3) { S = 16; wtab = wt3; ea = ea3; n = idx - N1 - N2; }
    else return;
    int x = n % S, y = (n / S) % S, g = n / (S * S);
    int o = g % L_OR, b = g / L_OR;
    const int szx = N_BL * S * (S - 1);
    const int basex = (g * S + y) * (S - 1);
    float wxm = (x > 0)     ? ea[basex + x - 1] : 0.f;
    float wxp = (x < S - 1) ? ea[szx + basex + x] : 0.f;
    float wym = (y > 0)     ? ea[2 * szx + (g * (S - 1) + y - 1) * S + x] : 0.f;
    float wyp = (y < S - 1) ? ea[3 * szx + (g * (S - 1) + y) * S + x] : 0.f;
    int op_ = (o == 0) ? L_OR - 1 : o - 1;
    int on_ = (o == L_OR - 1) ? 0 : o + 1;
    int sp = ((b * L_OR + op_) * S + y) * S + x;
    int sn = ((b * L_OR + on_) * S + y) * S + x;
    float wom = ea[4 * szx + sp];
    float wop = ea[4 * szx + N_BL * S * S + n];
    float* w = wtab + (size_t)n * 8;
    w[0] = wxm; w[1] = wxp; w[2] = wym; w[3] = wyp; w[4] = wom; w[5] = wop;
    ((int*)w)[6] = sp - n;
    ((int*)w)[7] = sn - n;
}

// ---------------------------------------------------------------------------
// bf16 Laplacian on cat: cat[:,outSlot] = alpha*L(cat[:,inSlot]) - cat[:,tppSlot]
// ---------------------------------------------------------------------------
template<int S>
__global__ __launch_bounds__(256)
void lap128b(u16* __restrict__ cat, int outSlot, int inSlot, int tppSlot,
             const float* __restrict__ wtab, float alpha)
{
    const int NN = N_BL * S * S;
    int node = blockIdx.x * 16 + (threadIdx.x >> 4);
    int c8   = threadIdx.x & 15;

    float4 wa = *(const float4*)(wtab + (size_t)node * 8);
    float4 wb = *(const float4*)(wtab + (size_t)node * 8 + 4);
    int dsp = __float_as_int(wb.z);
    int dsn = __float_as_int(wb.w);
    int sxm = (node > 0)      ? node - 1 : 0;
    int sxp = (node < NN - 1) ? node + 1 : node;
    int sym = (node >= S)     ? node - S : node;
    int syp = (node < NN - S) ? node + S : node;

    const int chOff = inSlot * 128 + c8 * 8;
    float a[8] = {0.f, 0.f, 0.f, 0.f, 0.f, 0.f, 0.f, 0.f};
    auto gather = [&](int src, float w) {
        s8v v = *(const s8v*)(cat + (size_t)src * 768 + chOff);
#pragma unroll
        for (int j = 0; j < 8; ++j) a[j] += w * b2f((u16)v[j]);
    };
    gather(sxm, wa.x); gather(sxp, wa.y); gather(sym, wa.z); gather(syp, wa.w);
    gather(node + dsp, wb.x); gather(node + dsn, wb.y);

    float r[8];
#pragma unroll
    for (int j = 0; j < 8; ++j) r[j] = alpha * a[j];
    if (tppSlot >= 0) {
        s8v t = *(const s8v*)(cat + (size_t)node * 768 + tppSlot * 128 + c8 * 8);
#pragma unroll
        for (int j = 0; j < 8; ++j) r[j] -= b2f((u16)t[j]);
    }
    uint4 ov;
    asm("v_cvt_pk_bf16_f32 %0, %1, %2" : "=v"(ov.x) : "v"(r[0]), "v"(r[1]));
    asm("v_cvt_pk_bf16_f32 %0, %1, %2" : "=v"(ov.y) : "v"(r[2]), "v"(r[3]));
    asm("v_cvt_pk_bf16_f32 %0, %1, %2" : "=v"(ov.z) : "v"(r[4]), "v"(r[5]));
    asm("v_cvt_pk_bf16_f32 %0, %1, %2" : "=v"(ov.w) : "v"(r[6]), "v"(r[7]));
    *(uint4*)(cat + (size_t)node * 768 + outSlot * 128 + c8 * 8) = ov;
}

// ---------------------------------------------------------------------------
// Fused BN+ReLU + first lap: h = max(O*sc+so,0);  writes T0=h and T1=L(h).
// ---------------------------------------------------------------------------
template<int S>
__global__ __launch_bounds__(256)
void lap1bn(u16* __restrict__ cat, const u16* __restrict__ O,
            int t0Slot, int t1Slot, const float* __restrict__ wtab,
            const float* __restrict__ gsc, const float* __restrict__ gso)
{
    const int NN = N_BL * S * S;
    int node = blockIdx.x * 16 + (threadIdx.x >> 4);
    int c8   = threadIdx.x & 15;

    float4 wa = *(const float4*)(wtab + (size_t)node * 8);
    float4 wb = *(const float4*)(wtab + (size_t)node * 8 + 4);
    int dsp = __float_as_int(wb.z);
    int dsn = __float_as_int(wb.w);
    int sxm = (node > 0)      ? node - 1 : 0;
    int sxp = (node < NN - 1) ? node + 1 : node;
    int sym = (node >= S)     ? node - S : node;
    int syp = (node < NN - S) ? node + S : node;

    float sc[8], so[8];
    {
        float4 s0 = *(const float4*)(gsc + c8 * 8);
        float4 s1 = *(const float4*)(gsc + c8 * 8 + 4);
        float4 o0 = *(const float4*)(gso + c8 * 8);
        float4 o1 = *(const float4*)(gso + c8 * 8 + 4);
        sc[0]=s0.x; sc[1]=s0.y; sc[2]=s0.z; sc[3]=s0.w;
        sc[4]=s1.x; sc[5]=s1.y; sc[6]=s1.z; sc[7]=s1.w;
        so[0]=o0.x; so[1]=o0.y; so[2]=o0.z; so[3]=o0.w;
        so[4]=o1.x; so[5]=o1.y; so[6]=o1.z; so[7]=o1.w;
    }

    float a[8] = {0.f, 0.f, 0.f, 0.f, 0.f, 0.f, 0.f, 0.f};
    auto gatherbn = [&](int src, float w) {
        s8v v = *(const s8v*)(O + (size_t)src * 128 + c8 * 8);
#pragma unroll
        for (int j = 0; j < 8; ++j)
            a[j] += w * fmaxf(b2f((u16)v[j]) * sc[j] + so[j], 0.f);
    };
    gatherbn(sxm, wa.x); gatherbn(sxp, wa.y); gatherbn(sym, wa.z); gatherbn(syp, wa.w);
    gatherbn(node + dsp, wb.x); gatherbn(node + dsn, wb.y);

    float t0[8];
    {
        s8v v = *(const s8v*)(O + (size_t)node * 128 + c8 * 8);
#pragma unroll
        for (int j = 0; j < 8; ++j)
            t0[j] = fmaxf(b2f((u16)v[j]) * sc[j] + so[j], 0.f);
    }
    uint4 o0v, o1v;
    asm("v_cvt_pk_bf16_f32 %0, %1, %2" : "=v"(o0v.x) : "v"(t0[0]), "v"(t0[1]));
    asm("v_cvt_pk_bf16_f32 %0, %1, %2" : "=v"(o0v.y) : "v"(t0[2]), "v"(t0[3]));
    asm("v_cvt_pk_bf16_f32 %0, %1, %2" : "=v"(o0v.z) : "v"(t0[4]), "v"(t0[5]));
    asm("v_cvt_pk_bf16_f32 %0, %1, %2" : "=v"(o0v.w) : "v"(t0[6]), "v"(t0[7]));
    asm("v_cvt_pk_bf16_f32 %0, %1, %2" : "=v"(o1v.x) : "v"(a[0]), "v"(a[1]));
    asm("v_cvt_pk_bf16_f32 %0, %1, %2" : "=v"(o1v.y) : "v"(a[2]), "v"(a[3]));
    asm("v_cvt_pk_bf16_f32 %0, %1, %2" : "=v"(o1v.z) : "v"(a[4]), "v"(a[5]));
    asm("v_cvt_pk_bf16_f32 %0, %1, %2" : "=v"(o1v.w) : "v"(a[6]), "v"(a[7]));
    *(uint4*)(cat + (size_t)node * 768 + t0Slot * 128 + c8 * 8) = o0v;
    *(uint4*)(cat + (size_t)node * 768 + t1Slot * 128 + c8 * 8) = o1v;
}

// fp32 laplacian for layer 1 (D=3), wtab-based
template<int S>
__global__ __launch_bounds__(256)
void lap3_kernel(float* __restrict__ out, const float* __restrict__ in,
                 const float* __restrict__ tpp, const float* __restrict__ wtab,
                 float alpha)
{
    const int NN = N_BL * S * S;
    int n = blockIdx.x * 256 + threadIdx.x;
    if (n >= NN) return;
    float4 wa = *(const float4*)(wtab + (size_t)n * 8);
    float4 wb = *(const float4*)(wtab + (size_t)n * 8 + 4);
    int dsp = __float_as_int(wb.z);
    int dsn = __float_as_int(wb.w);
    int sxm = (n > 0)      ? n - 1 : 0;
    int sxp = (n < NN - 1) ? n + 1 : n;
    int sym = (n >= S)     ? n - S : n;
    int syp = (n < NN - S) ? n + S : n;

    float a0 = 0.f, a1 = 0.f, a2 = 0.f;
    auto gather = [&](int src, float w) {
        a0 += w * in[src * 3 + 0];
        a1 += w * in[src * 3 + 1];
        a2 += w * in[src * 3 + 2];
    };
    gather(sxm, wa.x); gather(sxp, wa.y); gather(sym, wa.z); gather(syp, wa.w);
    gather(n + dsp, wb.x); gather(n + dsn, wb.y);

    float r0 = alpha * a0, r1 = alpha * a1, r2 = alpha * a2;
    if (tpp) { r0 -= tpp[n * 3 + 0]; r1 -= tpp[n * 3 + 1]; r2 -= tpp[n * 3 + 2]; }
    out[n * 3 + 0] = r0; out[n * 3 + 1] = r1; out[n * 3 + 2] = r2;
}

// ---------------------------------------------------------------------------
// MFMA GEMM + fused BN-stats.  O[N,128](bf16) = cat[N,768](bf16) @ W + bias.
// B staged via global_load_lds DMA (wave-uniform LDS base + lane*16, linear
// source) into double-buffered 16KB phases. ONE __syncthreads per phase: its
// implicit vmcnt(0) drain is the wait for the next phase's DMA (issued at the
// top of this phase, covered by 32 MFMAs). No ds_write, no staging VGPRs.
// ---------------------------------------------------------------------------
__global__ __launch_bounds__(256)
void gemm_mfma_cat(u16* __restrict__ O, const u16* __restrict__ A,
                   const u16* __restrict__ Bf, const float* __restrict__ bias,
                   float* __restrict__ partials)
{
    __shared__ u16 Bs[2][8192];               // 2 x 16KB
    const int tid  = threadIdx.x;
    const int wave = tid >> 6;
    const int lane = tid & 63;
    const int lrow = lane & 15;
    const int kg   = lane >> 4;
    const int r0   = blockIdx.x * 128 + wave * 32;

    const u16* A0 = A + (size_t)(r0 + lrow) * 768 + kg * 8;
    const u16* A1 = A0 + (size_t)16 * 768;

    f4v acc[2][8] = {};

    // DMA one 16KB phase q into Bs[slot]; each wave stages its 4KB quarter
    // as 4 x 1KB chunks (lane l -> dst + l*16, src per-lane + l*16).
    auto stage = [&](int q, int slot) {
        const char* src = (const char*)(Bf + q * 8192) + wave * 4096 + lane * 16;
        char* dstb = (char*)(&Bs[slot][0]) + wave * 4096;
#pragma unroll
        for (int i = 0; i < 4; ++i)
            __builtin_amdgcn_global_load_lds(
                (const __attribute__((address_space(1))) unsigned*)(src + i * 1024),
                (__attribute__((address_space(3))) unsigned*)(dstb + i * 1024),
                16, 0, 0);
    };

    // prologue: phase 0 via DMA; A frags for phase 0 (both k-subphases)
    stage(0, 0);
    s8v a00 = *(const s8v*)(A0);
    s8v a10 = *(const s8v*)(A1);
    s8v a01 = *(const s8v*)(A0 + 32);
    s8v a11 = *(const s8v*)(A1 + 32);
    __syncthreads();

#pragma unroll 1
    for (int p = 0; p < 12; ++p) {
        stage(p + 1, (p + 1) & 1);            // last iter reads 16KB pad of g_Bt
        s8v na00 = *(const s8v*)(A0 + (p + 1) * 64);
        s8v na10 = *(const s8v*)(A1 + (p + 1) * 64);
        s8v na01 = *(const s8v*)(A0 + (p + 1) * 64 + 32);
        s8v na11 = *(const s8v*)(A1 + (p + 1) * 64 + 32);
        const u16* bsl = &Bs[p & 1][0];
#pragma unroll
        for (int ct = 0; ct < 8; ++ct) {
            s8v b = *(const s8v*)&bsl[(ct * 64 + lane) * 8];
            acc[0][ct] = __builtin_amdgcn_mfma_f32_16x16x32_bf16(a00, b, acc[0][ct], 0, 0, 0);
            acc[1][ct] = __builtin_amdgcn_mfma_f32_16x16x32_bf16(a10, b, acc[1][ct], 0, 0, 0);
        }
#pragma unroll
        for (int ct = 0; ct < 8; ++ct) {
            s8v b = *(const s8v*)&bsl[4096 + (ct * 64 + lane) * 8];
            acc[0][ct] = __builtin_amdgcn_mfma_f32_16x16x32_bf16(a01, b, acc[0][ct], 0, 0, 0);
            acc[1][ct] = __builtin_amdgcn_mfma_f32_16x16x32_bf16(a11, b, acc[1][ct], 0, 0, 0);
        }
        __syncthreads();                      // drains DMA for phase p+1, retires reads
        a00 = na00; a10 = na10; a01 = na01; a11 = na11;
    }

    __shared__ float sred[4][2][8][16];
    float cs[8], cq[8];
#pragma unroll
    for (int ct = 0; ct < 8; ++ct) { cs[ct] = 0.f; cq[ct] = 0.f; }

#pragma unroll
    for (int s = 0; s < 2; ++s)
#pragma unroll
        for (int ct = 0; ct < 8; ++ct) {
            int col = ct * 16 + lrow;
            float bv = bias[col];
#pragma unroll
            for (int j = 0; j < 4; ++j) {
                int row = r0 + s * 16 + kg * 4 + j;
                float v = acc[s][ct][j] + bv;
                O[(size_t)row * 128 + col] = f2b(v);
                cs[ct] += v; cq[ct] += v * v;
            }
        }
#pragma unroll
    for (int ct = 0; ct < 8; ++ct) {
        cs[ct] += __shfl_xor(cs[ct], 16); cs[ct] += __shfl_xor(cs[ct], 32);
        cq[ct] += __shfl_xor(cq[ct], 16); cq[ct] += __shfl_xor(cq[ct], 32);
    }
    if (lane < 16) {
#pragma unroll
        for (int ct = 0; ct < 8; ++ct) {
            sred[wave][0][ct][lane] = cs[ct];
            sred[wave][1][ct][lane] = cq[ct];
        }
    }
    __syncthreads();
    if (threadIdx.x < 128) {
        int ct = threadIdx.x >> 4, lr = threadIdx.x & 15;
        float S = 0.f, Q = 0.f;
#pragma unroll
        for (int w = 0; w < 4; ++w) { S += sred[w][0][ct][lr]; Q += sred[w][1][ct][lr]; }
        partials[blockIdx.x * 256 + threadIdx.x]       = S;
        partials[blockIdx.x * 256 + 128 + threadIdx.x] = Q;
    }
}

// all weight prep in one launch; blockIdx.y = 0..3 -> W2..W5, 4 -> W6
__global__ __launch_bounds__(256)
void wprep_all(const float* __restrict__ W2, const float* __restrict__ W3,
               const float* __restrict__ W4, const float* __restrict__ W5,
               const float* __restrict__ W6, u16* __restrict__ Bf,
               u16* __restrict__ W6t)
{
    int l = blockIdx.y;
    int idx = blockIdx.x * 256 + threadIdx.x;
    if (l == 4) {
        if (idx >= 16 * 768) return;
        int c = idx / 768, kk = idx % 768;
        int slot = kk >> 7, d = kk & 127;
        W6t[idx] = (c < 10) ? f2b(W6[(size_t)slot * 1280 + d * 10 + c]) : (u16)0;
        return;
    }
    const float* W = (l == 0) ? W2 : (l == 1) ? W3 : (l == 2) ? W4 : W5;
    int base = (l & 1) ? 5 : 0;
    int j    = idx & 7;
    int lane = (idx >> 3) & 63;
    int ct   = (idx >> 9) & 7;
    int k0s  = idx >> 12;
    int k    = k0s * 32 + (lane >> 4) * 8 + j;
    int col  = ct * 16 + (lane & 15);
    int slot = k >> 7, d = k & 127;
    int wk = slot - base; if (wk < 0) wk += 6;
    Bf[(size_t)l * LSTRIDE + idx] = f2b(W[(size_t)wk * 16384 + d * 128 + col]);
}

// layer-1 GEMM + fused stats. Block = 128 rows; T values staged in LDS.
__global__ __launch_bounds__(256)
void l1gemm(u16* __restrict__ O, const float* __restrict__ T0,
            const float* __restrict__ Tt, const float* __restrict__ W,
            const float* __restrict__ bias, float* __restrict__ partials)
{
    __shared__ float Ts[128][18];
    __shared__ float sh[2][128], sh2[2][128];
    int tid = threadIdx.x;
    int rbase = blockIdx.x * 128;
    for (int i = tid; i < 128 * 18; i += 256) {
        int r = i / 18, t = i % 18;
        int k = t / 3, j = t % 3;
        Ts[r][t] = (k == 0) ? T0[(size_t)(rbase + r) * 3 + j]
                            : Tt[(size_t)(k - 1) * N1 * 3 + (size_t)(rbase + r) * 3 + j];
    }
    __syncthreads();
    int c = tid & 127, h = tid >> 7;
    float w[18];
#pragma unroll
    for (int k = 0; k < 6; ++k)
#pragma unroll
        for (int j = 0; j < 3; ++j) w[k * 3 + j] = W[(size_t)k * 384 + j * 128 + c];
    float bv = bias[c];
    float S = 0.f, Q = 0.f;
    for (int i = 0; i < 64; ++i) {
        int r = h * 64 + i;
        float acc = bv;
#pragma unroll
        for (int t = 0; t < 18; ++t) acc += Ts[r][t] * w[t];
        O[(size_t)(rbase + r) * 128 + c] = f2b(acc);
        S += acc; Q += acc * acc;
    }
    sh[h][c] = S; sh2[h][c] = Q;
    __syncthreads();
    if (tid < 128) {
        partials[blockIdx.x * 256 + tid]       = sh[0][tid] + sh[1][tid];
        partials[blockIdx.x * 256 + 128 + tid] = sh2[0][tid] + sh2[1][tid];
    }
}

// layer-6 GEMM + bias + relu
__global__ __launch_bounds__(256)
void out10_cat(float* __restrict__ O10, const u16* __restrict__ cat,
               const u16* __restrict__ W6t, const float* __restrict__ bias)
{
    int col = threadIdx.x & 15;
    int row = blockIdx.x * 16 + (threadIdx.x >> 4);
    const u16* a = cat + (size_t)row * 768;
    const u16* w = W6t + (size_t)col * 768;
    float acc = 0.f;
#pragma unroll 4
    for (int k0 = 0; k0 < 768; k0 += 8) {
        s8v av = *(const s8v*)(a + k0);
        s8v wv = *(const s8v*)(w + k0);
#pragma unroll
        for (int j = 0; j < 8; ++j)
            acc += b2f((u16)av[j]) * b2f((u16)wv[j]);
    }
    if (col < 10)
        O10[(size_t)row * 10 + col] = fmaxf(acc + bias[col], 0.f);
}

// ---------------------------------------------------------------------------
// Fused BN reduce: 64 blocks; stage-1 strided sums -> part2; last block
// (elected via atomic counter; deterministic output) finalizes gsc/gso.
// ---------------------------------------------------------------------------
__global__ __launch_bounds__(256)
void bn_reduce_f(const float* __restrict__ partials, int nblk, int N,
                 const float* __restrict__ g, const float* __restrict__ bt,
                 float* __restrict__ gsc, float* __restrict__ gso,
                 float* __restrict__ part2, unsigned* __restrict__ cnt)
{
    int tid = threadIdx.x;
    float S = 0.f;
#pragma unroll 4
    for (int b = blockIdx.x; b < nblk; b += 64)
        S += partials[(size_t)b * 256 + tid];
    part2[blockIdx.x * 256 + tid] = S;
    __threadfence();
    __syncthreads();
    __shared__ int last;
    if (tid == 0) last = (atomicAdd(cnt, 1u) == 63u) ? 1 : 0;
    __syncthreads();
    if (!last) return;
    __threadfence();
    int c = tid & 127, h = tid >> 7;
    float Sa = 0.f, Qa = 0.f;
#pragma unroll 8
    for (int b = h; b < 64; b += 2) {
        Sa += part2[b * 256 + c];
        Qa += part2[b * 256 + 128 + c];
    }
    __shared__ float shS[2][128], shQ[2][128];
    shS[h][c] = Sa; shQ[h][c] = Qa;
    __syncthreads();
    if (tid < 128) {
        float Sx = shS[0][tid] + shS[1][tid];
        float Qx = shQ[0][tid] + shQ[1][tid];
        float inv_n = 1.f / (float)N;
        float mu = Sx * inv_n;
        float var = Qx * inv_n - mu * mu;
        float is = rsqrtf(var + 1e-5f);
        float sc = is * g[tid];
        gsc[tid] = sc;
        gso[tid] = bt[tid] - mu * sc;
    }
    if (tid == 0) *cnt = 0u;
}

// BN + relu + 2x2 max-pool fused (8 channels/thread) using gsc/gso
__global__ __launch_bounds__(256)
void bn_apply_pool8(const u16* __restrict__ O, u16* __restrict__ cat, int outSlot,
                    int s, int Nout,
                    const float* __restrict__ gsc, const float* __restrict__ gso)
{
    int idx = blockIdx.x * 256 + threadIdx.x;    // over Nout*16
    if (idx >= Nout * 16) return;
    int c8 = idx & 15;
    int n2 = idx >> 4;
    int h  = s >> 1;
    int x2 = n2 % h;
    int y2 = (n2 / h) % h;
    int gg = n2 / (h * h);
    int base = (gg * s + 2 * y2) * s + 2 * x2;
    s8v v0 = *(const s8v*)(O + (size_t)base * 128 + c8 * 8);
    s8v v1 = *(const s8v*)(O + (size_t)(base + 1) * 128 + c8 * 8);
    s8v v2 = *(const s8v*)(O + (size_t)(base + s) * 128 + c8 * 8);
    s8v v3 = *(const s8v*)(O + (size_t)(base + s + 1) * 128 + c8 * 8);
    s8v ov;
#pragma unroll
    for (int j = 0; j < 8; ++j) {
        int c = c8 * 8 + j;
        float sc = gsc[c], so = gso[c];
        float m =          b2f((u16)v0[j]) * sc + so;
        m = fmaxf(m, b2f((u16)v1[j]) * sc + so);
        m = fmaxf(m, b2f((u16)v2[j]) * sc + so);
        m = fmaxf(m, b2f((u16)v3[j]) * sc + so);
        ov[j] = (short)f2b(fmaxf(m, 0.f));
    }
    *(s8v*)(cat + (size_t)n2 * 768 + outSlot * 128 + c8 * 8) = ov;
}

// fused tail: pool3(16->8) + orientation pool + global max + log_softmax
__global__ __launch_bounds__(512)
void tail_fused(const float* __restrict__ O10, float* __restrict__ out)
{
    __shared__ float p4[512][10];
    __shared__ float G[8][10];
    __shared__ float rowm[8], rowl[8];
    int t = threadIdx.x;
    for (int i = t; i < 5120; i += 512) {
        int c = i % 10, n = i / 10;
        int x = n & 7, y = (n >> 3) & 7, b = n >> 6;
        float m = -INFINITY;
        for (int o = 0; o < L_OR; ++o) {
            int base = ((b * L_OR + o) * 16 + 2 * y) * 16 + 2 * x;
            m = fmaxf(m, O10[(size_t)base * 10 + c]);
            m = fmaxf(m, O10[(size_t)(base + 1) * 10 + c]);
            m = fmaxf(m, O10[(size_t)(base + 16) * 10 + c]);
            m = fmaxf(m, O10[(size_t)(base + 17) * 10 + c]);
        }
        p4[n][c] = m;
    }
    __syncthreads();
    if (t < 80) {
        int b = t / 10, c = t % 10;
        float m = -INFINITY;
        for (int p = 0; p < 64; ++p) m = fmaxf(m, p4[b * 64 + p][c]);
        G[b][c] = m;
    }
    __syncthreads();
    if (t < 8) {
        float m = -INFINITY;
        for (int c = 0; c < 10; ++c) m = fmaxf(m, G[t][c]);
        float s = 0.f;
        for (int c = 0; c < 10; ++c) s += expf(G[t][c] - m);
        rowm[t] = m; rowl[t] = logf(s);
    }
    __syncthreads();
    if (t < 80) {
        int b = t / 10, c = t % 10;
        out[t] = G[b][c] - rowm[b] - rowl[b];
    }
}

// ---------------------------------------------------------------------------
// Host-side orchestration
// ---------------------------------------------------------------------------
static void launch_lapb(u16* cat, int os, int is, int ts, const float* wtab,
                        int S, int N, float alpha, hipStream_t st)
{
    dim3 grid(N / 16), block(256);
    if (S == 64)      hipLaunchKernelGGL(lap128b<64>, grid, block, 0, st, cat, os, is, ts, wtab, alpha);
    else if (S == 32) hipLaunchKernelGGL(lap128b<32>, grid, block, 0, st, cat, os, is, ts, wtab, alpha);
    else              hipLaunchKernelGGL(lap128b<16>, grid, block, 0, st, cat, os, is, ts, wtab, alpha);
}

static void cheb_laps_b5(u16* cat, const float* wtab, int S, int N, hipStream_t st)
{
    for (int k = 1; k < 6; ++k) {
        int os = (k + 5) % 6;
        int is = (k - 1 + 5) % 6;
        int ts = (k >= 2) ? (k - 2 + 5) % 6 : -1;
        launch_lapb(cat, os, is, ts, wtab, S, N, (k == 1) ? 1.f : 2.f, st);
    }
}

static void cheb_laps_2to5(u16* cat, const float* wtab, int S, int N, hipStream_t st)
{
    for (int k = 2; k < 6; ++k)
        launch_lapb(cat, k, k - 1, k - 2, wtab, S, N, 2.f, st);
}

static void launch_lap1bn(u16* cat, const u16* O, const float* wtab,
                          const float* gsc, const float* gso,
                          int S, int N, hipStream_t st)
{
    dim3 grid(N / 16), block(256);
    if (S == 64)      hipLaunchKernelGGL(lap1bn<64>, grid, block, 0, st, cat, O, 0, 1, wtab, gsc, gso);
    else if (S == 32) hipLaunchKernelGGL(lap1bn<32>, grid, block, 0, st, cat, O, 0, 1, wtab, gsc, gso);
    else              hipLaunchKernelGGL(lap1bn<16>, grid, block, 0, st, cat, O, 0, 1, wtab, gsc, gso);
}

extern "C" void kernel_launch(void* const* d_in, const int* in_sizes, int n_in,
                              void* d_out, int out_size, void* d_ws, size_t ws_size,
                              hipStream_t stream)
{
    const float* x   = (const float*)d_in[0];
    const float* ea1 = (const float*)d_in[2];
    const float* ea2 = (const float*)d_in[4];
    const float* ea3 = (const float*)d_in[6];
    const float* W1  = (const float*)d_in[12];
    const float* b1  = (const float*)d_in[13];
    const float* W2  = (const float*)d_in[14];
    const float* b2  = (const float*)d_in[15];
    const float* W3  = (const float*)d_in[16];
    const float* b3  = (const float*)d_in[17];
    const float* W4  = (const float*)d_in[18];
    const float* b4  = (const float*)d_in[19];
    const float* W5  = (const float*)d_in[20];
    const float* b5  = (const float*)d_in[21];
    const float* W6  = (const float*)d_in[22];
    const float* b6  = (const float*)d_in[23];
    const float* g1  = (const float*)d_in[24];
    const float* be1 = (const float*)d_in[25];
    const float* g2  = (const float*)d_in[26];
    const float* be2 = (const float*)d_in[27];
    const float* g3  = (const float*)d_in[28];
    const float* be3 = (const float*)d_in[29];
    const float* g4  = (const float*)d_in[30];
    const float* be4 = (const float*)d_in[31];
    const float* g5  = (const float*)d_in[32];
    const float* be5 = (const float*)d_in[33];

    u16 *cat, *O, *Bt, *W6t;
    float *Tt, *O10, *part, *part2, *gsc, *gso, *wt1, *wt2, *wt3;
    unsigned* cnt;
    if (hipGetSymbolAddress((void**)&cat, HIP_SYMBOL(g_cat)) != hipSuccess) return;
    if (hipGetSymbolAddress((void**)&O,   HIP_SYMBOL(g_O))   != hipSuccess) return;
    if (hipGetSymbolAddress((void**)&Tt,  HIP_SYMBOL(g_Tt))  != hipSuccess) return;
    if (hipGetSymbolAddress((void**)&Bt,  HIP_SYMBOL(g_Bt))  != hipSuccess) return;
    if (hipGetSymbolAddress((void**)&W6t, HIP_SYMBOL(g_W6t)) != hipSuccess) return;
    if (hipGetSymbolAddress((void**)&O10, HIP_SYMBOL(g_O10)) != hipSuccess) return;
    if (hipGetSymbolAddress((void**)&part,  HIP_SYMBOL(g_part))  != hipSuccess) return;
    if (hipGetSymbolAddress((void**)&part2, HIP_SYMBOL(g_part2)) != hipSuccess) return;
    if (hipGetSymbolAddress((void**)&gsc, HIP_SYMBOL(g_gsc)) != hipSuccess) return;
    if (hipGetSymbolAddress((void**)&gso, HIP_SYMBOL(g_gso)) != hipSuccess) return;
    if (hipGetSymbolAddress((void**)&wt1, HIP_SYMBOL(g_wt1)) != hipSuccess) return;
    if (hipGetSymbolAddress((void**)&wt2, HIP_SYMBOL(g_wt2)) != hipSuccess) return;
    if (hipGetSymbolAddress((void**)&wt3, HIP_SYMBOL(g_wt3)) != hipSuccess) return;
    if (hipGetSymbolAddress((void**)&cnt, HIP_SYMBOL(g_cnt)) != hipSuccess) return;

    dim3 blk(256);

    // ---------- prep ----------
    hipLaunchKernelGGL(eaprep_all, dim3((N1 + N2 + N3) / 256), blk, 0, stream,
                       wt1, wt2, wt3, ea1, ea2, ea3);
    hipLaunchKernelGGL(wprep_all, dim3(384, 5), blk, 0, stream, W2, W3, W4, W5, W6, Bt, W6t);

    // ---------- Layer 1: cheb(x[N1,3], W1) -> O bf16 (+stats) ----------
    {
        float* t1 = Tt;
        float* t2 = Tt + (size_t)N1 * 3;
        float* t3 = Tt + (size_t)2 * N1 * 3;
        float* t4 = Tt + (size_t)3 * N1 * 3;
        float* t5 = Tt + (size_t)4 * N1 * 3;
        dim3 gl((N1 + 255) / 256);
        hipLaunchKernelGGL(lap3_kernel<64>, gl, blk, 0, stream, t1, x,  (const float*)nullptr, wt1, 1.f);
        hipLaunchKernelGGL(lap3_kernel<64>, gl, blk, 0, stream, t2, t1, x,  wt1, 2.f);
        hipLaunchKernelGGL(lap3_kernel<64>, gl, blk, 0, stream, t3, t2, t1, wt1, 2.f);
        hipLaunchKernelGGL(lap3_kernel<64>, gl, blk, 0, stream, t4, t3, t2, wt1, 2.f);
        hipLaunchKernelGGL(lap3_kernel<64>, gl, blk, 0, stream, t5, t4, t3, wt1, 2.f);
        hipLaunchKernelGGL(l1gemm, dim3(N1 / 128), blk, 0, stream, O, x, Tt, W1, b1, part);
    }
    hipLaunchKernelGGL(bn_reduce_f, dim3(64), blk, 0, stream, part, N1 / 128, N1,
                       g1, be1, gsc, gso, part2, cnt);

    // ---------- Layer 2 (N1): fused BN-lap, laps, GEMM ----------
    launch_lap1bn(cat, O, wt1, gsc, gso, 64, N1, stream);
    cheb_laps_2to5(cat, wt1, 64, N1, stream);
    hipLaunchKernelGGL(gemm_mfma_cat, dim3(N1 / 128), blk, 0, stream, O, cat, Bt, b2, part);
    hipLaunchKernelGGL(bn_reduce_f, dim3(64), blk, 0, stream, part, N1 / 128, N1,
                       g2, be2, gsc, gso, part2, cnt);
    hipLaunchKernelGGL(bn_apply_pool8, dim3(N2 / 16), blk, 0, stream,
                       O, cat, 5, 64, N2, gsc, gso);

    // ---------- Layer 3 (N2, base 5) ----------
    cheb_laps_b5(cat, wt2, 32, N2, stream);
    hipLaunchKernelGGL(gemm_mfma_cat, dim3(N2 / 128), blk, 0, stream, O, cat, Bt + 1 * LSTRIDE, b3, part);
    hipLaunchKernelGGL(bn_reduce_f, dim3(64), blk, 0, stream, part, N2 / 128, N2,
                       g3, be3, gsc, gso, part2, cnt);

    // ---------- Layer 4 (N2, base 0) ----------
    launch_lap1bn(cat, O, wt2, gsc, gso, 32, N2, stream);
    cheb_laps_2to5(cat, wt2, 32, N2, stream);
    hipLaunchKernelGGL(gemm_mfma_cat, dim3(N2 / 128), blk, 0, stream, O, cat, Bt + 2 * LSTRIDE, b4, part);
    hipLaunchKernelGGL(bn_reduce_f, dim3(64), blk, 0, stream, part, N2 / 128, N2,
                       g4, be4, gsc, gso, part2, cnt);
    hipLaunchKernelGGL(bn_apply_pool8, dim3(N3 / 16), blk, 0, stream,
                       O, cat, 5, 32, N3, gsc, gso);

    // ---------- Layer 5 (N3, base 5) ----------
    cheb_laps_b5(cat, wt3, 16, N3, stream);
    hipLaunchKernelGGL(gemm_mfma_cat, dim3(N3 / 128), blk, 0, stream, O, cat, Bt + 3 * LSTRIDE, b5, part);
    hipLaunchKernelGGL(bn_reduce_f, dim3(64), blk, 0, stream, part, N3 / 128, N3,
                       g5, be5, gsc, gso, part2, cnt);

    // ---------- Layer 6 (N3, base 0, out 10, relu fused) ----------
    launch_lap1bn(cat, O, wt3, gsc, gso, 16, N3, stream);
    cheb_laps_2to5(cat, wt3, 16, N3, stream);
    hipLaunchKernelGGL(out10_cat, dim3(N3 / 16), blk, 0, stream, O10, cat, W6t, b6);

    // ---------- fused tail ----------
    hipLaunchKernelGGL(tail_fused, dim3(1), dim3(512), 0, stream, O10, (float*)d_out);
}

// Round 12
// 748.767 us; speedup vs baseline: 1.0619x; 1.0619x over previous
//
#include <hip/hip_runtime.h>
#include <math.h>

#define L_OR 6
#define N_BL 48   // B*L = 8*6

typedef unsigned short u16;
typedef __attribute__((ext_vector_type(8))) short s8v;   // 8 x bf16 (16B)
typedef __attribute__((ext_vector_type(4))) float f4v;

#define N1 196608
#define N2 49152
#define N3 12288
#define LSTRIDE 114688   // u16 stride per layer in g_Bt (96K data + 16K pad)

// ---- static device workspace (BSS, allocated at module load) ----
__device__ u16   g_cat[(size_t)N1 * 768 + 1024];  // 302 MB: 6 T-slots bf16 (+pad)
__device__ u16   g_O[(size_t)N1 * 128];           // 50 MB: GEMM output bf16
__device__ float g_Tt[5 * (size_t)N1 * 3];        // layer-1 T1..T5 fp32
__device__ u16   g_Bt[4 * LSTRIDE];               // fragment-ordered weights, W2..W5
__device__ u16   g_W6t[16 * 768];                 // layer-6 weights (padded cols)
__device__ float g_wt1[(size_t)N1 * 8];           // edge-weight tables per scale
__device__ float g_wt2[(size_t)N2 * 8];
__device__ float g_wt3[(size_t)N3 * 8];
__device__ float g_O10[(size_t)N3 * 10];
__device__ float g_part[1536 * 256];              // per-block BN partials
__device__ float g_part2[64 * 256];               // stage-2 BN partials
__device__ float g_gsc[128];                      // BN combined scale
__device__ float g_gso[128];                      // BN combined offset

__device__ __forceinline__ float b2f(u16 v) {
    return __uint_as_float(((unsigned)v) << 16);
}
__device__ __forceinline__ u16 f2b(float f) {
    unsigned u = __float_as_uint(f);
    return (u16)((u + 0x7FFFu + ((u >> 16) & 1u)) >> 16);   // RNE
}

// ---------------------------------------------------------------------------
// Edge-weight tables, all three scales in one launch.
// ---------------------------------------------------------------------------
__global__ __launch_bounds__(256)
void eaprep_all(float* __restrict__ wt1, float* __restrict__ wt2,
                float* __restrict__ wt3, const float* __restrict__ ea1,
                const float* __restrict__ ea2, const float* __restrict__ ea3)
{
    int idx = blockIdx.x * 256 + threadIdx.x;
    int S, n; float* wtab; const float* ea;
    if (idx < N1)            { S = 64; wtab = wt1; ea = ea1; n = idx; }
    else if (idx < N1 + N2)  { S = 32; wtab = wt2; ea = ea2; n = idx - N1; }
    else if (idx < N1 + N2 + N3) { S = 16; wtab = wt3; ea = ea3; n = idx - N1 - N2; }
    else return;
    int x = n % S, y = (n / S) % S, g = n / (S * S);
    int o = g % L_OR, b = g / L_OR;
    const int szx = N_BL * S * (S - 1);
    const int basex = (g * S + y) * (S - 1);
    float wxm = (x > 0)     ? ea[basex + x - 1] : 0.f;
    float wxp = (x < S - 1) ? ea[szx + basex + x] : 0.f;
    float wym = (y > 0)     ? ea[2 * szx + (g * (S - 1) + y - 1) * S + x] : 0.f;
    float wyp = (y < S - 1) ? ea[3 * szx + (g * (S - 1) + y) * S + x] : 0.f;
    int op_ = (o == 0) ? L_OR - 1 : o - 1;
    int on_ = (o == L_OR - 1) ? 0 : o + 1;
    int sp = ((b * L_OR + op_) * S + y) * S + x;
    int sn = ((b * L_OR + on_) * S + y) * S + x;
    float wom = ea[4 * szx + sp];
    float wop = ea[4 * szx + N_BL * S * S + n];
    float* w = wtab + (size_t)n * 8;
    w[0] = wxm; w[1] = wxp; w[2] = wym; w[3] = wyp; w[4] = wom; w[5] = wop;
    ((int*)w)[6] = sp - n;
    ((int*)w)[7] = sn - n;
}

// ---------------------------------------------------------------------------
// bf16 Laplacian on cat: cat[:,outSlot] = alpha*L(cat[:,inSlot]) - cat[:,tppSlot]
// ---------------------------------------------------------------------------
template<int S>
__global__ __launch_bounds__(256)
void lap128b(u16* __restrict__ cat, int outSlot, int inSlot, int tppSlot,
             const float* __restrict__ wtab, float alpha)
{
    const int NN = N_BL * S * S;
    int node = blockIdx.x * 16 + (threadIdx.x >> 4);
    int c8   = threadIdx.x & 15;

    float4 wa = *(const float4*)(wtab + (size_t)node * 8);
    float4 wb = *(const float4*)(wtab + (size_t)node * 8 + 4);
    int dsp = __float_as_int(wb.z);
    int dsn = __float_as_int(wb.w);
    int sxm = (node > 0)      ? node - 1 : 0;
    int sxp = (node < NN - 1) ? node + 1 : node;
    int sym = (node >= S)     ? node - S : node;
    int syp = (node < NN - S) ? node + S : node;

    const int chOff = inSlot * 128 + c8 * 8;
    float a[8] = {0.f, 0.f, 0.f, 0.f, 0.f, 0.f, 0.f, 0.f};
    auto gather = [&](int src, float w) {
        s8v v = *(const s8v*)(cat + (size_t)src * 768 + chOff);
#pragma unroll
        for (int j = 0; j < 8; ++j) a[j] += w * b2f((u16)v[j]);
    };
    gather(sxm, wa.x); gather(sxp, wa.y); gather(sym, wa.z); gather(syp, wa.w);
    gather(node + dsp, wb.x); gather(node + dsn, wb.y);

    float r[8];
#pragma unroll
    for (int j = 0; j < 8; ++j) r[j] = alpha * a[j];
    if (tppSlot >= 0) {
        s8v t = *(const s8v*)(cat + (size_t)node * 768 + tppSlot * 128 + c8 * 8);
#pragma unroll
        for (int j = 0; j < 8; ++j) r[j] -= b2f((u16)t[j]);
    }
    uint4 ov;
    asm("v_cvt_pk_bf16_f32 %0, %1, %2" : "=v"(ov.x) : "v"(r[0]), "v"(r[1]));
    asm("v_cvt_pk_bf16_f32 %0, %1, %2" : "=v"(ov.y) : "v"(r[2]), "v"(r[3]));
    asm("v_cvt_pk_bf16_f32 %0, %1, %2" : "=v"(ov.z) : "v"(r[4]), "v"(r[5]));
    asm("v_cvt_pk_bf16_f32 %0, %1, %2" : "=v"(ov.w) : "v"(r[6]), "v"(r[7]));
    *(uint4*)(cat + (size_t)node * 768 + outSlot * 128 + c8 * 8) = ov;
}

// ---------------------------------------------------------------------------
// Fused BN+ReLU + first lap: h = max(O*sc+so,0);  writes T0=h and T1=L(h).
// ---------------------------------------------------------------------------
template<int S>
__global__ __launch_bounds__(256)
void lap1bn(u16* __restrict__ cat, const u16* __restrict__ O,
            int t0Slot, int t1Slot, const float* __restrict__ wtab,
            const float* __restrict__ gsc, const float* __restrict__ gso)
{
    const int NN = N_BL * S * S;
    int node = blockIdx.x * 16 + (threadIdx.x >> 4);
    int c8   = threadIdx.x & 15;

    float4 wa = *(const float4*)(wtab + (size_t)node * 8);
    float4 wb = *(const float4*)(wtab + (size_t)node * 8 + 4);
    int dsp = __float_as_int(wb.z);
    int dsn = __float_as_int(wb.w);
    int sxm = (node > 0)      ? node - 1 : 0;
    int sxp = (node < NN - 1) ? node + 1 : node;
    int sym = (node >= S)     ? node - S : node;
    int syp = (node < NN - S) ? node + S : node;

    float sc[8], so[8];
    {
        float4 s0 = *(const float4*)(gsc + c8 * 8);
        float4 s1 = *(const float4*)(gsc + c8 * 8 + 4);
        float4 o0 = *(const float4*)(gso + c8 * 8);
        float4 o1 = *(const float4*)(gso + c8 * 8 + 4);
        sc[0]=s0.x; sc[1]=s0.y; sc[2]=s0.z; sc[3]=s0.w;
        sc[4]=s1.x; sc[5]=s1.y; sc[6]=s1.z; sc[7]=s1.w;
        so[0]=o0.x; so[1]=o0.y; so[2]=o0.z; so[3]=o0.w;
        so[4]=o1.x; so[5]=o1.y; so[6]=o1.z; so[7]=o1.w;
    }

    float a[8] = {0.f, 0.f, 0.f, 0.f, 0.f, 0.f, 0.f, 0.f};
    auto gatherbn = [&](int src, float w) {
        s8v v = *(const s8v*)(O + (size_t)src * 128 + c8 * 8);
#pragma unroll
        for (int j = 0; j < 8; ++j)
            a[j] += w * fmaxf(b2f((u16)v[j]) * sc[j] + so[j], 0.f);
    };
    gatherbn(sxm, wa.x); gatherbn(sxp, wa.y); gatherbn(sym, wa.z); gatherbn(syp, wa.w);
    gatherbn(node + dsp, wb.x); gatherbn(node + dsn, wb.y);

    float t0[8];
    {
        s8v v = *(const s8v*)(O + (size_t)node * 128 + c8 * 8);
#pragma unroll
        for (int j = 0; j < 8; ++j)
            t0[j] = fmaxf(b2f((u16)v[j]) * sc[j] + so[j], 0.f);
    }
    uint4 o0v, o1v;
    asm("v_cvt_pk_bf16_f32 %0, %1, %2" : "=v"(o0v.x) : "v"(t0[0]), "v"(t0[1]));
    asm("v_cvt_pk_bf16_f32 %0, %1, %2" : "=v"(o0v.y) : "v"(t0[2]), "v"(t0[3]));
    asm("v_cvt_pk_bf16_f32 %0, %1, %2" : "=v"(o0v.z) : "v"(t0[4]), "v"(t0[5]));
    asm("v_cvt_pk_bf16_f32 %0, %1, %2" : "=v"(o0v.w) : "v"(t0[6]), "v"(t0[7]));
    asm("v_cvt_pk_bf16_f32 %0, %1, %2" : "=v"(o1v.x) : "v"(a[0]), "v"(a[1]));
    asm("v_cvt_pk_bf16_f32 %0, %1, %2" : "=v"(o1v.y) : "v"(a[2]), "v"(a[3]));
    asm("v_cvt_pk_bf16_f32 %0, %1, %2" : "=v"(o1v.z) : "v"(a[4]), "v"(a[5]));
    asm("v_cvt_pk_bf16_f32 %0, %1, %2" : "=v"(o1v.w) : "v"(a[6]), "v"(a[7]));
    *(uint4*)(cat + (size_t)node * 768 + t0Slot * 128 + c8 * 8) = o0v;
    *(uint4*)(cat + (size_t)node * 768 + t1Slot * 128 + c8 * 8) = o1v;
}

// fp32 laplacian for layer 1 (D=3), wtab-based
template<int S>
__global__ __launch_bounds__(256)
void lap3_kernel(float* __restrict__ out, const float* __restrict__ in,
                 const float* __restrict__ tpp, const float* __restrict__ wtab,
                 float alpha)
{
    const int NN = N_BL * S * S;
    int n = blockIdx.x * 256 + threadIdx.x;
    if (n >= NN) return;
    float4 wa = *(const float4*)(wtab + (size_t)n * 8);
    float4 wb = *(const float4*)(wtab + (size_t)n * 8 + 4);
    int dsp = __float_as_int(wb.z);
    int dsn = __float_as_int(wb.w);
    int sxm = (n > 0)      ? n - 1 : 0;
    int sxp = (n < NN - 1) ? n + 1 : n;
    int sym = (n >= S)     ? n - S : n;
    int syp = (n < NN - S) ? n + S : n;

    float a0 = 0.f, a1 = 0.f, a2 = 0.f;
    auto gather = [&](int src, float w) {
        a0 += w * in[src * 3 + 0];
        a1 += w * in[src * 3 + 1];
        a2 += w * in[src * 3 + 2];
    };
    gather(sxm, wa.x); gather(sxp, wa.y); gather(sym, wa.z); gather(syp, wa.w);
    gather(n + dsp, wb.x); gather(n + dsn, wb.y);

    float r0 = alpha * a0, r1 = alpha * a1, r2 = alpha * a2;
    if (tpp) { r0 -= tpp[n * 3 + 0]; r1 -= tpp[n * 3 + 1]; r2 -= tpp[n * 3 + 2]; }
    out[n * 3 + 0] = r0; out[n * 3 + 1] = r1; out[n * 3 + 2] = r2;
}

// ---------------------------------------------------------------------------
// MFMA GEMM + fused BN-stats (r8 structure — best measured: 92 us @N1).
// B staged 16KB/phase in double-buffered LDS (2 k-subphases per barrier pair).
// ---------------------------------------------------------------------------
__global__ __launch_bounds__(256)
void gemm_mfma_cat(u16* __restrict__ O, const u16* __restrict__ A,
                   const u16* __restrict__ Bf, const float* __restrict__ bias,
                   float* __restrict__ partials)
{
    __shared__ u16 Bs[2][8192];               // 2 x 16KB
    const int tid  = threadIdx.x;
    const int wave = tid >> 6;
    const int lane = tid & 63;
    const int lrow = lane & 15;
    const int kg   = lane >> 4;
    const int r0   = blockIdx.x * 128 + wave * 32;

    const u16* A0 = A + (size_t)(r0 + lrow) * 768 + kg * 8;
    const u16* A1 = A0 + (size_t)16 * 768;

    f4v acc[2][8] = {};

    // prologue: stage phase 0 (16KB), load A for both subphases
#pragma unroll
    for (int i = 0; i < 4; ++i)
        *(s8v*)&Bs[0][i * 2048 + tid * 8] = *(const s8v*)(Bf + i * 2048 + tid * 8);
    s8v a00 = *(const s8v*)(A0);
    s8v a10 = *(const s8v*)(A1);
    s8v a01 = *(const s8v*)(A0 + 32);
    s8v a11 = *(const s8v*)(A1 + 32);
    __syncthreads();

#pragma unroll 1
    for (int p = 0; p < 12; ++p) {
        const int cur = p & 1, nxt = cur ^ 1;
        const u16* src = Bf + (p + 1) * 8192;
        s8v nb0 = *(const s8v*)(src + tid * 8);
        s8v nb1 = *(const s8v*)(src + 2048 + tid * 8);
        s8v nb2 = *(const s8v*)(src + 4096 + tid * 8);
        s8v nb3 = *(const s8v*)(src + 6144 + tid * 8);
        s8v na00 = *(const s8v*)(A0 + (p + 1) * 64);
        s8v na10 = *(const s8v*)(A1 + (p + 1) * 64);
        s8v na01 = *(const s8v*)(A0 + (p + 1) * 64 + 32);
        s8v na11 = *(const s8v*)(A1 + (p + 1) * 64 + 32);
        // subphase 0
#pragma unroll
        for (int ct = 0; ct < 8; ++ct) {
            s8v b = *(const s8v*)&Bs[cur][(ct * 64 + lane) * 8];
            acc[0][ct] = __builtin_amdgcn_mfma_f32_16x16x32_bf16(a00, b, acc[0][ct], 0, 0, 0);
            acc[1][ct] = __builtin_amdgcn_mfma_f32_16x16x32_bf16(a10, b, acc[1][ct], 0, 0, 0);
        }
        // subphase 1
#pragma unroll
        for (int ct = 0; ct < 8; ++ct) {
            s8v b = *(const s8v*)&Bs[cur][4096 + (ct * 64 + lane) * 8];
            acc[0][ct] = __builtin_amdgcn_mfma_f32_16x16x32_bf16(a01, b, acc[0][ct], 0, 0, 0);
            acc[1][ct] = __builtin_amdgcn_mfma_f32_16x16x32_bf16(a11, b, acc[1][ct], 0, 0, 0);
        }
        __syncthreads();                      // readers of Bs[nxt] done
        *(s8v*)&Bs[nxt][tid * 8]        = nb0;
        *(s8v*)&Bs[nxt][2048 + tid * 8] = nb1;
        *(s8v*)&Bs[nxt][4096 + tid * 8] = nb2;
        *(s8v*)&Bs[nxt][6144 + tid * 8] = nb3;
        __syncthreads();                      // Bs[nxt] published
        a00 = na00; a10 = na10; a01 = na01; a11 = na11;
    }

    __shared__ float sred[4][2][8][16];
    float cs[8], cq[8];
#pragma unroll
    for (int ct = 0; ct < 8; ++ct) { cs[ct] = 0.f; cq[ct] = 0.f; }

#pragma unroll
    for (int s = 0; s < 2; ++s)
#pragma unroll
        for (int ct = 0; ct < 8; ++ct) {
            int col = ct * 16 + lrow;
            float bv = bias[col];
#pragma unroll
            for (int j = 0; j < 4; ++j) {
                int row = r0 + s * 16 + kg * 4 + j;
                float v = acc[s][ct][j] + bv;
                O[(size_t)row * 128 + col] = f2b(v);
                cs[ct] += v; cq[ct] += v * v;
            }
        }
#pragma unroll
    for (int ct = 0; ct < 8; ++ct) {
        cs[ct] += __shfl_xor(cs[ct], 16); cs[ct] += __shfl_xor(cs[ct], 32);
        cq[ct] += __shfl_xor(cq[ct], 16); cq[ct] += __shfl_xor(cq[ct], 32);
    }
    if (lane < 16) {
#pragma unroll
        for (int ct = 0; ct < 8; ++ct) {
            sred[wave][0][ct][lane] = cs[ct];
            sred[wave][1][ct][lane] = cq[ct];
        }
    }
    __syncthreads();
    if (threadIdx.x < 128) {
        int ct = threadIdx.x >> 4, lr = threadIdx.x & 15;
        float S = 0.f, Q = 0.f;
#pragma unroll
        for (int w = 0; w < 4; ++w) { S += sred[w][0][ct][lr]; Q += sred[w][1][ct][lr]; }
        partials[blockIdx.x * 256 + threadIdx.x]       = S;
        partials[blockIdx.x * 256 + 128 + threadIdx.x] = Q;
    }
}

// all weight prep in one launch; blockIdx.y = 0..3 -> W2..W5, 4 -> W6
__global__ __launch_bounds__(256)
void wprep_all(const float* __restrict__ W2, const float* __restrict__ W3,
               const float* __restrict__ W4, const float* __restrict__ W5,
               const float* __restrict__ W6, u16* __restrict__ Bf,
               u16* __restrict__ W6t)
{
    int l = blockIdx.y;
    int idx = blockIdx.x * 256 + threadIdx.x;
    if (l == 4) {
        if (idx >= 16 * 768) return;
        int c = idx / 768, kk = idx % 768;
        int slot = kk >> 7, d = kk & 127;
        W6t[idx] = (c < 10) ? f2b(W6[(size_t)slot * 1280 + d * 10 + c]) : (u16)0;
        return;
    }
    const float* W = (l == 0) ? W2 : (l == 1) ? W3 : (l == 2) ? W4 : W5;
    int base = (l & 1) ? 5 : 0;
    int j    = idx & 7;
    int lane = (idx >> 3) & 63;
    int ct   = (idx >> 9) & 7;
    int k0s  = idx >> 12;
    int k    = k0s * 32 + (lane >> 4) * 8 + j;
    int col  = ct * 16 + (lane & 15);
    int slot = k >> 7, d = k & 127;
    int wk = slot - base; if (wk < 0) wk += 6;
    Bf[(size_t)l * LSTRIDE + idx] = f2b(W[(size_t)wk * 16384 + d * 128 + col]);
}

// layer-1 GEMM + fused stats. Block = 128 rows; T values staged in LDS.
__global__ __launch_bounds__(256)
void l1gemm(u16* __restrict__ O, const float* __restrict__ T0,
            const float* __restrict__ Tt, const float* __restrict__ W,
            const float* __restrict__ bias, float* __restrict__ partials)
{
    __shared__ float Ts[128][18];
    __shared__ float sh[2][128], sh2[2][128];
    int tid = threadIdx.x;
    int rbase = blockIdx.x * 128;
    for (int i = tid; i < 128 * 18; i += 256) {
        int r = i / 18, t = i % 18;
        int k = t / 3, j = t % 3;
        Ts[r][t] = (k == 0) ? T0[(size_t)(rbase + r) * 3 + j]
                            : Tt[(size_t)(k - 1) * N1 * 3 + (size_t)(rbase + r) * 3 + j];
    }
    __syncthreads();
    int c = tid & 127, h = tid >> 7;
    float w[18];
#pragma unroll
    for (int k = 0; k < 6; ++k)
#pragma unroll
        for (int j = 0; j < 3; ++j) w[k * 3 + j] = W[(size_t)k * 384 + j * 128 + c];
    float bv = bias[c];
    float S = 0.f, Q = 0.f;
    for (int i = 0; i < 64; ++i) {
        int r = h * 64 + i;
        float acc = bv;
#pragma unroll
        for (int t = 0; t < 18; ++t) acc += Ts[r][t] * w[t];
        O[(size_t)(rbase + r) * 128 + c] = f2b(acc);
        S += acc; Q += acc * acc;
    }
    sh[h][c] = S; sh2[h][c] = Q;
    __syncthreads();
    if (tid < 128) {
        partials[blockIdx.x * 256 + tid]       = sh[0][tid] + sh[1][tid];
        partials[blockIdx.x * 256 + 128 + tid] = sh2[0][tid] + sh2[1][tid];
    }
}

// layer-6 GEMM + bias + relu
__global__ __launch_bounds__(256)
void out10_cat(float* __restrict__ O10, const u16* __restrict__ cat,
               const u16* __restrict__ W6t, const float* __restrict__ bias)
{
    int col = threadIdx.x & 15;
    int row = blockIdx.x * 16 + (threadIdx.x >> 4);
    const u16* a = cat + (size_t)row * 768;
    const u16* w = W6t + (size_t)col * 768;
    float acc = 0.f;
#pragma unroll 4
    for (int k0 = 0; k0 < 768; k0 += 8) {
        s8v av = *(const s8v*)(a + k0);
        s8v wv = *(const s8v*)(w + k0);
#pragma unroll
        for (int j = 0; j < 8; ++j)
            acc += b2f((u16)av[j]) * b2f((u16)wv[j]);
    }
    if (col < 10)
        O10[(size_t)row * 10 + col] = fmaxf(acc + bias[col], 0.f);
}

// BN reduce stage 1: 64 blocks; block i sums records {i, i+64, ...}
__global__ __launch_bounds__(256)
void bn_reduce1(const float* __restrict__ partials, int nblk,
                float* __restrict__ part2)
{
    int tid = threadIdx.x;
    float S = 0.f;
#pragma unroll 4
    for (int b = blockIdx.x; b < nblk; b += 64)
        S += partials[(size_t)b * 256 + tid];
    part2[blockIdx.x * 256 + tid] = S;
}

// BN reduce stage 2: -> combined scale gsc = invstd*gamma, gso = beta - mean*gsc
__global__ __launch_bounds__(256)
void bn_finalize2(const float* __restrict__ part2, int N,
                  const float* __restrict__ g, const float* __restrict__ bt,
                  float* __restrict__ gsc, float* __restrict__ gso)
{
    int tid = threadIdx.x;
    int c = tid & 127, h = tid >> 7;
    float S = 0.f, Q = 0.f;
#pragma unroll 8
    for (int b = h; b < 64; b += 2) {
        S += part2[b * 256 + c];
        Q += part2[b * 256 + 128 + c];
    }
    __shared__ float shS[2][128], shQ[2][128];
    shS[h][c] = S; shQ[h][c] = Q;
    __syncthreads();
    if (tid < 128) {
        float Sa = shS[0][tid] + shS[1][tid];
        float Qa = shQ[0][tid] + shQ[1][tid];
        float inv_n = 1.f / (float)N;
        float mu = Sa * inv_n;
        float var = Qa * inv_n - mu * mu;
        float is = rsqrtf(var + 1e-5f);
        float sc = is * g[tid];
        gsc[tid] = sc;
        gso[tid] = bt[tid] - mu * sc;
    }
}

// BN + relu + 2x2 max-pool fused (8 channels/thread) using gsc/gso
__global__ __launch_bounds__(256)
void bn_apply_pool8(const u16* __restrict__ O, u16* __restrict__ cat, int outSlot,
                    int s, int Nout,
                    const float* __restrict__ gsc, const float* __restrict__ gso)
{
    int idx = blockIdx.x * 256 + threadIdx.x;    // over Nout*16
    if (idx >= Nout * 16) return;
    int c8 = idx & 15;
    int n2 = idx >> 4;
    int h  = s >> 1;
    int x2 = n2 % h;
    int y2 = (n2 / h) % h;
    int gg = n2 / (h * h);
    int base = (gg * s + 2 * y2) * s + 2 * x2;
    s8v v0 = *(const s8v*)(O + (size_t)base * 128 + c8 * 8);
    s8v v1 = *(const s8v*)(O + (size_t)(base + 1) * 128 + c8 * 8);
    s8v v2 = *(const s8v*)(O + (size_t)(base + s) * 128 + c8 * 8);
    s8v v3 = *(const s8v*)(O + (size_t)(base + s + 1) * 128 + c8 * 8);
    s8v ov;
#pragma unroll
    for (int j = 0; j < 8; ++j) {
        int c = c8 * 8 + j;
        float sc = gsc[c], so = gso[c];
        float m =          b2f((u16)v0[j]) * sc + so;
        m = fmaxf(m, b2f((u16)v1[j]) * sc + so);
        m = fmaxf(m, b2f((u16)v2[j]) * sc + so);
        m = fmaxf(m, b2f((u16)v3[j]) * sc + so);
        ov[j] = (short)f2b(fmaxf(m, 0.f));
    }
    *(s8v*)(cat + (size_t)n2 * 768 + outSlot * 128 + c8 * 8) = ov;
}

// fused tail: pool3(16->8) + orientation pool + global max + log_softmax
__global__ __launch_bounds__(512)
void tail_fused(const float* __restrict__ O10, float* __restrict__ out)
{
    __shared__ float p4[512][10];
    __shared__ float G[8][10];
    __shared__ float rowm[8], rowl[8];
    int t = threadIdx.x;
    for (int i = t; i < 5120; i += 512) {
        int c = i % 10, n = i / 10;
        int x = n & 7, y = (n >> 3) & 7, b = n >> 6;
        float m = -INFINITY;
        for (int o = 0; o < L_OR; ++o) {
            int base = ((b * L_OR + o) * 16 + 2 * y) * 16 + 2 * x;
            m = fmaxf(m, O10[(size_t)base * 10 + c]);
            m = fmaxf(m, O10[(size_t)(base + 1) * 10 + c]);
            m = fmaxf(m, O10[(size_t)(base + 16) * 10 + c]);
            m = fmaxf(m, O10[(size_t)(base + 17) * 10 + c]);
        }
        p4[n][c] = m;
    }
    __syncthreads();
    if (t < 80) {
        int b = t / 10, c = t % 10;
        float m = -INFINITY;
        for (int p = 0; p < 64; ++p) m = fmaxf(m, p4[b * 64 + p][c]);
        G[b][c] = m;
    }
    __syncthreads();
    if (t < 8) {
        float m = -INFINITY;
        for (int c = 0; c < 10; ++c) m = fmaxf(m, G[t][c]);
        float s = 0.f;
        for (int c = 0; c < 10; ++c) s += expf(G[t][c] - m);
        rowm[t] = m; rowl[t] = logf(s);
    }
    __syncthreads();
    if (t < 80) {
        int b = t / 10, c = t % 10;
        out[t] = G[b][c] - rowm[b] - rowl[b];
    }
}

// ---------------------------------------------------------------------------
// Host-side orchestration
// ---------------------------------------------------------------------------
static void launch_lapb(u16* cat, int os, int is, int ts, const float* wtab,
                        int S, int N, float alpha, hipStream_t st)
{
    dim3 grid(N / 16), block(256);
    if (S == 64)      hipLaunchKernelGGL(lap128b<64>, grid, block, 0, st, cat, os, is, ts, wtab, alpha);
    else if (S == 32) hipLaunchKernelGGL(lap128b<32>, grid, block, 0, st, cat, os, is, ts, wtab, alpha);
    else              hipLaunchKernelGGL(lap128b<16>, grid, block, 0, st, cat, os, is, ts, wtab, alpha);
}

static void cheb_laps_b5(u16* cat, const float* wtab, int S, int N, hipStream_t st)
{
    for (int k = 1; k < 6; ++k) {
        int os = (k + 5) % 6;
        int is = (k - 1 + 5) % 6;
        int ts = (k >= 2) ? (k - 2 + 5) % 6 : -1;
        launch_lapb(cat, os, is, ts, wtab, S, N, (k == 1) ? 1.f : 2.f, st);
    }
}

static void cheb_laps_2to5(u16* cat, const float* wtab, int S, int N, hipStream_t st)
{
    for (int k = 2; k < 6; ++k)
        launch_lapb(cat, k, k - 1, k - 2, wtab, S, N, 2.f, st);
}

static void launch_lap1bn(u16* cat, const u16* O, const float* wtab,
                          const float* gsc, const float* gso,
                          int S, int N, hipStream_t st)
{
    dim3 grid(N / 16), block(256);
    if (S == 64)      hipLaunchKernelGGL(lap1bn<64>, grid, block, 0, st, cat, O, 0, 1, wtab, gsc, gso);
    else if (S == 32) hipLaunchKernelGGL(lap1bn<32>, grid, block, 0, st, cat, O, 0, 1, wtab, gsc, gso);
    else              hipLaunchKernelGGL(lap1bn<16>, grid, block, 0, st, cat, O, 0, 1, wtab, gsc, gso);
}

static void bn_reduce(float* part, float* part2, int nblk, int N,
                      const float* g, const float* bt,
                      float* gsc, float* gso, hipStream_t st)
{
    hipLaunchKernelGGL(bn_reduce1, dim3(64), dim3(256), 0, st, part, nblk, part2);
    hipLaunchKernelGGL(bn_finalize2, dim3(1), dim3(256), 0, st, part2, N, g, bt, gsc, gso);
}

extern "C" void kernel_launch(void* const* d_in, const int* in_sizes, int n_in,
                              void* d_out, int out_size, void* d_ws, size_t ws_size,
                              hipStream_t stream)
{
    const float* x   = (const float*)d_in[0];
    const float* ea1 = (const float*)d_in[2];
    const float* ea2 = (const float*)d_in[4];
    const float* ea3 = (const float*)d_in[6];
    const float* W1  = (const float*)d_in[12];
    const float* b1  = (const float*)d_in[13];
    const float* W2  = (const float*)d_in[14];
    const float* b2  = (const float*)d_in[15];
    const float* W3  = (const float*)d_in[16];
    const float* b3  = (const float*)d_in[17];
    const float* W4  = (const float*)d_in[18];
    const float* b4  = (const float*)d_in[19];
    const float* W5  = (const float*)d_in[20];
    const float* b5  = (const float*)d_in[21];
    const float* W6  = (const float*)d_in[22];
    const float* b6  = (const float*)d_in[23];
    const float* g1  = (const float*)d_in[24];
    const float* be1 = (const float*)d_in[25];
    const float* g2  = (const float*)d_in[26];
    const float* be2 = (const float*)d_in[27];
    const float* g3  = (const float*)d_in[28];
    const float* be3 = (const float*)d_in[29];
    const float* g4  = (const float*)d_in[30];
    const float* be4 = (const float*)d_in[31];
    const float* g5  = (const float*)d_in[32];
    const float* be5 = (const float*)d_in[33];

    u16 *cat, *O, *Bt, *W6t;
    float *Tt, *O10, *part, *part2, *gsc, *gso, *wt1, *wt2, *wt3;
    if (hipGetSymbolAddress((void**)&cat, HIP_SYMBOL(g_cat)) != hipSuccess) return;
    if (hipGetSymbolAddress((void**)&O,   HIP_SYMBOL(g_O))   != hipSuccess) return;
    if (hipGetSymbolAddress((void**)&Tt,  HIP_SYMBOL(g_Tt))  != hipSuccess) return;
    if (hipGetSymbolAddress((void**)&Bt,  HIP_SYMBOL(g_Bt))  != hipSuccess) return;
    if (hipGetSymbolAddress((void**)&W6t, HIP_SYMBOL(g_W6t)) != hipSuccess) return;
    if (hipGetSymbolAddress((void**)&O10, HIP_SYMBOL(g_O10)) != hipSuccess) return;
    if (hipGetSymbolAddress((void**)&part,  HIP_SYMBOL(g_part))  != hipSuccess) return;
    if (hipGetSymbolAddress((void**)&part2, HIP_SYMBOL(g_part2)) != hipSuccess) return;
    if (hipGetSymbolAddress((void**)&gsc, HIP_SYMBOL(g_gsc)) != hipSuccess) return;
    if (hipGetSymbolAddress((void**)&gso, HIP_SYMBOL(g_gso)) != hipSuccess) return;
    if (hipGetSymbolAddress((void**)&wt1, HIP_SYMBOL(g_wt1)) != hipSuccess) return;
    if (hipGetSymbolAddress((void**)&wt2, HIP_SYMBOL(g_wt2)) != hipSuccess) return;
    if (hipGetSymbolAddress((void**)&wt3, HIP_SYMBOL(g_wt3)) != hipSuccess) return;

    dim3 blk(256);

    // ---------- prep ----------
    hipLaunchKernelGGL(eaprep_all, dim3((N1 + N2 + N3) / 256), blk, 0, stream,
                       wt1, wt2, wt3, ea1, ea2, ea3);
    hipLaunchKernelGGL(wprep_all, dim3(384, 5), blk, 0, stream, W2, W3, W4, W5, W6, Bt, W6t);

    // ---------- Layer 1: cheb(x[N1,3], W1) -> O bf16 (+stats) ----------
    {
        float* t1 = Tt;
        float* t2 = Tt + (size_t)N1 * 3;
        float* t3 = Tt + (size_t)2 * N1 * 3;
        float* t4 = Tt + (size_t)3 * N1 * 3;
        float* t5 = Tt + (size_t)4 * N1 * 3;
        dim3 gl((N1 + 255) / 256);
        hipLaunchKernelGGL(lap3_kernel<64>, gl, blk, 0, stream, t1, x,  (const float*)nullptr, wt1, 1.f);
        hipLaunchKernelGGL(lap3_kernel<64>, gl, blk, 0, stream, t2, t1, x,  wt1, 2.f);
        hipLaunchKernelGGL(lap3_kernel<64>, gl, blk, 0, stream, t3, t2, t1, wt1, 2.f);
        hipLaunchKernelGGL(lap3_kernel<64>, gl, blk, 0, stream, t4, t3, t2, wt1, 2.f);
        hipLaunchKernelGGL(lap3_kernel<64>, gl, blk, 0, stream, t5, t4, t3, wt1, 2.f);
        hipLaunchKernelGGL(l1gemm, dim3(N1 / 128), blk, 0, stream, O, x, Tt, W1, b1, part);
    }
    bn_reduce(part, part2, N1 / 128, N1, g1, be1, gsc, gso, stream);

    // ---------- Layer 2 (N1): fused BN-lap, laps, GEMM ----------
    launch_lap1bn(cat, O, wt1, gsc, gso, 64, N1, stream);
    cheb_laps_2to5(cat, wt1, 64, N1, stream);
    hipLaunchKernelGGL(gemm_mfma_cat, dim3(N1 / 128), blk, 0, stream, O, cat, Bt, b2, part);
    bn_reduce(part, part2, N1 / 128, N1, g2, be2, gsc, gso, stream);
    hipLaunchKernelGGL(bn_apply_pool8, dim3(N2 / 16), blk, 0, stream,
                       O, cat, 5, 64, N2, gsc, gso);

    // ---------- Layer 3 (N2, base 5) ----------
    cheb_laps_b5(cat, wt2, 32, N2, stream);
    hipLaunchKernelGGL(gemm_mfma_cat, dim3(N2 / 128), blk, 0, stream, O, cat, Bt + 1 * LSTRIDE, b3, part);
    bn_reduce(part, part2, N2 / 128, N2, g3, be3, gsc, gso, stream);

    // ---------- Layer 4 (N2, base 0) ----------
    launch_lap1bn(cat, O, wt2, gsc, gso, 32, N2, stream);
    cheb_laps_2to5(cat, wt2, 32, N2, stream);
    hipLaunchKernelGGL(gemm_mfma_cat, dim3(N2 / 128), blk, 0, stream, O, cat, Bt + 2 * LSTRIDE, b4, part);
    bn_reduce(part, part2, N2 / 128, N2, g4, be4, gsc, gso, stream);
    hipLaunchKernelGGL(bn_apply_pool8, dim3(N3 / 16), blk, 0, stream,
                       O, cat, 5, 32, N3, gsc, gso);

    // ---------- Layer 5 (N3, base 5) ----------
    cheb_laps_b5(cat, wt3, 16, N3, stream);
    hipLaunchKernelGGL(gemm_mfma_cat, dim3(N3 / 128), blk, 0, stream, O, cat, Bt + 3 * LSTRIDE, b5, part);
    bn_reduce(part, part2, N3 / 128, N3, g5, be5, gsc, gso, stream);

    // ---------- Layer 6 (N3, base 0, out 10, relu fused) ----------
    launch_lap1bn(cat, O, wt3, gsc, gso, 16, N3, stream);
    cheb_laps_2to5(cat, wt3, 16, N3, stream);
    hipLaunchKernelGGL(out10_cat, dim3(N3 / 16), blk, 0, stream, O10, cat, W6t, b6);

    // ---------- fused tail ----------
    hipLaunchKernelGGL(tail_fused, dim3(1), dim3(512), 0, stream, O10, (float*)d_out);
}

// Round 13
// 736.089 us; speedup vs baseline: 1.0802x; 1.0172x over previous
//
#include <hip/hip_runtime.h>
#include <math.h>

#define L_OR 6
#define N_BL 48   // B*L = 8*6

typedef unsigned short u16;
typedef __attribute__((ext_vector_type(8))) short s8v;   // 8 x bf16 (16B)
typedef __attribute__((ext_vector_type(4))) float f4v;

#define N1 196608
#define N2 49152
#define N3 12288
#define LSTRIDE 114688   // u16 stride per layer in g_Bt (96K data + 16K pad)

// ---- static device workspace (BSS, allocated at module load) ----
__device__ u16   g_cat[(size_t)N1 * 768 + 1024];  // 302 MB: 6 T-slots bf16 (+pad)
__device__ u16   g_O[(size_t)N1 * 128];           // 50 MB: GEMM output bf16
__device__ float g_Tt[5 * (size_t)N1 * 3];        // layer-1 T1..T5 fp32
__device__ u16   g_Bt[4 * LSTRIDE];               // fragment-ordered weights, W2..W5
__device__ u16   g_W6t[16 * 768];                 // layer-6 weights (padded cols)
__device__ float g_wt1[(size_t)N1 * 8];           // edge-weight tables per scale
__device__ float g_wt2[(size_t)N2 * 8];
__device__ float g_wt3[(size_t)N3 * 8];
__device__ float g_O10[(size_t)N3 * 10];
__device__ float g_part[1536 * 256];              // per-block BN partials
__device__ float g_part2[64 * 256];               // stage-2 BN partials
__device__ float g_gsc[128];                      // BN combined scale
__device__ float g_gso[128];                      // BN combined offset
__device__ unsigned g_cnt;                        // last-block-done counter

__device__ __forceinline__ float b2f(u16 v) {
    return __uint_as_float(((unsigned)v) << 16);
}
__device__ __forceinline__ u16 f2b(float f) {
    unsigned u = __float_as_uint(f);
    return (u16)((u + 0x7FFFu + ((u >> 16) & 1u)) >> 16);   // RNE
}

// ---------------------------------------------------------------------------
// Edge-weight tables, all three scales in one launch.
// ---------------------------------------------------------------------------
__global__ __launch_bounds__(256)
void eaprep_all(float* __restrict__ wt1, float* __restrict__ wt2,
                float* __restrict__ wt3, const float* __restrict__ ea1,
                const float* __restrict__ ea2, const float* __restrict__ ea3)
{
    int idx = blockIdx.x * 256 + threadIdx.x;
    int S, n; float* wtab; const float* ea;
    if (idx < N1)            { S = 64; wtab = wt1; ea = ea1; n = idx; }
    else if (idx < N1 + N2)  { S = 32; wtab = wt2; ea = ea2; n = idx - N1; }
    else if (idx < N1 + N2 + N3) { S = 16; wtab = wt3; ea = ea3; n = idx - N1 - N2; }
    else return;
    int x = n % S, y = (n / S) % S, g = n / (S * S);
    int o = g % L_OR, b = g / L_OR;
    const int szx = N_BL * S * (S - 1);
    const int basex = (g * S + y) * (S - 1);
    float wxm = (x > 0)     ? ea[basex + x - 1] : 0.f;
    float wxp = (x < S - 1) ? ea[szx + basex + x] : 0.f;
    float wym = (y > 0)     ? ea[2 * szx + (g * (S - 1) + y - 1) * S + x] : 0.f;
    float wyp = (y < S - 1) ? ea[3 * szx + (g * (S - 1) + y) * S + x] : 0.f;
    int op_ = (o == 0) ? L_OR - 1 : o - 1;
    int on_ = (o == L_OR - 1) ? 0 : o + 1;
    int sp = ((b * L_OR + op_) * S + y) * S + x;
    int sn = ((b * L_OR + on_) * S + y) * S + x;
    float wom = ea[4 * szx + sp];
    float wop = ea[4 * szx + N_BL * S * S + n];
    float* w = wtab + (size_t)n * 8;
    w[0] = wxm; w[1] = wxp; w[2] = wym; w[3] = wyp; w[4] = wom; w[5] = wop;
    ((int*)w)[6] = sp - n;
    ((int*)w)[7] = sn - n;
}

// ---------------------------------------------------------------------------
// bf16 Laplacian on cat: cat[:,outSlot] = alpha*L(cat[:,inSlot]) - cat[:,tppSlot]
// XCD-chunked blockIdx swizzle: each XCD works a contiguous node chunk so
// y-/o-neighbor gather reuse stays in its private L2.
// ---------------------------------------------------------------------------
template<int S>
__global__ __launch_bounds__(256)
void lap128b(u16* __restrict__ cat, int outSlot, int inSlot, int tppSlot,
             const float* __restrict__ wtab, float alpha)
{
    const int NN  = N_BL * S * S;
    const int NWG = NN / 16;                       // divisible by 8 at all scales
    int bid = blockIdx.x;
    int sb  = (bid & 7) * (NWG >> 3) + (bid >> 3); // bijective chunked swizzle
    int node = sb * 16 + (threadIdx.x >> 4);
    int c8   = threadIdx.x & 15;

    float4 wa = *(const float4*)(wtab + (size_t)node * 8);
    float4 wb = *(const float4*)(wtab + (size_t)node * 8 + 4);
    int dsp = __float_as_int(wb.z);
    int dsn = __float_as_int(wb.w);
    int sxm = (node > 0)      ? node - 1 : 0;
    int sxp = (node < NN - 1) ? node + 1 : node;
    int sym = (node >= S)     ? node - S : node;
    int syp = (node < NN - S) ? node + S : node;

    const int chOff = inSlot * 128 + c8 * 8;
    float a[8] = {0.f, 0.f, 0.f, 0.f, 0.f, 0.f, 0.f, 0.f};
    auto gather = [&](int src, float w) {
        s8v v = *(const s8v*)(cat + (size_t)src * 768 + chOff);
#pragma unroll
        for (int j = 0; j < 8; ++j) a[j] += w * b2f((u16)v[j]);
    };
    gather(sxm, wa.x); gather(sxp, wa.y); gather(sym, wa.z); gather(syp, wa.w);
    gather(node + dsp, wb.x); gather(node + dsn, wb.y);

    float r[8];
#pragma unroll
    for (int j = 0; j < 8; ++j) r[j] = alpha * a[j];
    if (tppSlot >= 0) {
        s8v t = *(const s8v*)(cat + (size_t)node * 768 + tppSlot * 128 + c8 * 8);
#pragma unroll
        for (int j = 0; j < 8; ++j) r[j] -= b2f((u16)t[j]);
    }
    uint4 ov;
    asm("v_cvt_pk_bf16_f32 %0, %1, %2" : "=v"(ov.x) : "v"(r[0]), "v"(r[1]));
    asm("v_cvt_pk_bf16_f32 %0, %1, %2" : "=v"(ov.y) : "v"(r[2]), "v"(r[3]));
    asm("v_cvt_pk_bf16_f32 %0, %1, %2" : "=v"(ov.z) : "v"(r[4]), "v"(r[5]));
    asm("v_cvt_pk_bf16_f32 %0, %1, %2" : "=v"(ov.w) : "v"(r[6]), "v"(r[7]));
    *(uint4*)(cat + (size_t)node * 768 + outSlot * 128 + c8 * 8) = ov;
}

// ---------------------------------------------------------------------------
// Fused BN+ReLU + first lap: h = max(O*sc+so,0);  writes T0=h and T1=L(h).
// Same XCD-chunked swizzle as lap128b.
// ---------------------------------------------------------------------------
template<int S>
__global__ __launch_bounds__(256)
void lap1bn(u16* __restrict__ cat, const u16* __restrict__ O,
            int t0Slot, int t1Slot, const float* __restrict__ wtab,
            const float* __restrict__ gsc, const float* __restrict__ gso)
{
    const int NN  = N_BL * S * S;
    const int NWG = NN / 16;
    int bid = blockIdx.x;
    int sb  = (bid & 7) * (NWG >> 3) + (bid >> 3);
    int node = sb * 16 + (threadIdx.x >> 4);
    int c8   = threadIdx.x & 15;

    float4 wa = *(const float4*)(wtab + (size_t)node * 8);
    float4 wb = *(const float4*)(wtab + (size_t)node * 8 + 4);
    int dsp = __float_as_int(wb.z);
    int dsn = __float_as_int(wb.w);
    int sxm = (node > 0)      ? node - 1 : 0;
    int sxp = (node < NN - 1) ? node + 1 : node;
    int sym = (node >= S)     ? node - S : node;
    int syp = (node < NN - S) ? node + S : node;

    float sc[8], so[8];
    {
        float4 s0 = *(const float4*)(gsc + c8 * 8);
        float4 s1 = *(const float4*)(gsc + c8 * 8 + 4);
        float4 o0 = *(const float4*)(gso + c8 * 8);
        float4 o1 = *(const float4*)(gso + c8 * 8 + 4);
        sc[0]=s0.x; sc[1]=s0.y; sc[2]=s0.z; sc[3]=s0.w;
        sc[4]=s1.x; sc[5]=s1.y; sc[6]=s1.z; sc[7]=s1.w;
        so[0]=o0.x; so[1]=o0.y; so[2]=o0.z; so[3]=o0.w;
        so[4]=o1.x; so[5]=o1.y; so[6]=o1.z; so[7]=o1.w;
    }

    float a[8] = {0.f, 0.f, 0.f, 0.f, 0.f, 0.f, 0.f, 0.f};
    auto gatherbn = [&](int src, float w) {
        s8v v = *(const s8v*)(O + (size_t)src * 128 + c8 * 8);
#pragma unroll
        for (int j = 0; j < 8; ++j)
            a[j] += w * fmaxf(b2f((u16)v[j]) * sc[j] + so[j], 0.f);
    };
    gatherbn(sxm, wa.x); gatherbn(sxp, wa.y); gatherbn(sym, wa.z); gatherbn(syp, wa.w);
    gatherbn(node + dsp, wb.x); gatherbn(node + dsn, wb.y);

    float t0[8];
    {
        s8v v = *(const s8v*)(O + (size_t)node * 128 + c8 * 8);
#pragma unroll
        for (int j = 0; j < 8; ++j)
            t0[j] = fmaxf(b2f((u16)v[j]) * sc[j] + so[j], 0.f);
    }
    uint4 o0v, o1v;
    asm("v_cvt_pk_bf16_f32 %0, %1, %2" : "=v"(o0v.x) : "v"(t0[0]), "v"(t0[1]));
    asm("v_cvt_pk_bf16_f32 %0, %1, %2" : "=v"(o0v.y) : "v"(t0[2]), "v"(t0[3]));
    asm("v_cvt_pk_bf16_f32 %0, %1, %2" : "=v"(o0v.z) : "v"(t0[4]), "v"(t0[5]));
    asm("v_cvt_pk_bf16_f32 %0, %1, %2" : "=v"(o0v.w) : "v"(t0[6]), "v"(t0[7]));
    asm("v_cvt_pk_bf16_f32 %0, %1, %2" : "=v"(o1v.x) : "v"(a[0]), "v"(a[1]));
    asm("v_cvt_pk_bf16_f32 %0, %1, %2" : "=v"(o1v.y) : "v"(a[2]), "v"(a[3]));
    asm("v_cvt_pk_bf16_f32 %0, %1, %2" : "=v"(o1v.z) : "v"(a[4]), "v"(a[5]));
    asm("v_cvt_pk_bf16_f32 %0, %1, %2" : "=v"(o1v.w) : "v"(a[6]), "v"(a[7]));
    *(uint4*)(cat + (size_t)node * 768 + t0Slot * 128 + c8 * 8) = o0v;
    *(uint4*)(cat + (size_t)node * 768 + t1Slot * 128 + c8 * 8) = o1v;
}

// fp32 laplacian for layer 1 (D=3), wtab-based
template<int S>
__global__ __launch_bounds__(256)
void lap3_kernel(float* __restrict__ out, const float* __restrict__ in,
                 const float* __restrict__ tpp, const float* __restrict__ wtab,
                 float alpha)
{
    const int NN = N_BL * S * S;
    int n = blockIdx.x * 256 + threadIdx.x;
    if (n >= NN) return;
    float4 wa = *(const float4*)(wtab + (size_t)n * 8);
    float4 wb = *(const float4*)(wtab + (size_t)n * 8 + 4);
    int dsp = __float_as_int(wb.z);
    int dsn = __float_as_int(wb.w);
    int sxm = (n > 0)      ? n - 1 : 0;
    int sxp = (n < NN - 1) ? n + 1 : n;
    int sym = (n >= S)     ? n - S : n;
    int syp = (n < NN - S) ? n + S : n;

    float a0 = 0.f, a1 = 0.f, a2 = 0.f;
    auto gather = [&](int src, float w) {
        a0 += w * in[src * 3 + 0];
        a1 += w * in[src * 3 + 1];
        a2 += w * in[src * 3 + 2];
    };
    gather(sxm, wa.x); gather(sxp, wa.y); gather(sym, wa.z); gather(syp, wa.w);
    gather(n + dsp, wb.x); gather(n + dsn, wb.y);

    float r0 = alpha * a0, r1 = alpha * a1, r2 = alpha * a2;
    if (tpp) { r0 -= tpp[n * 3 + 0]; r1 -= tpp[n * 3 + 1]; r2 -= tpp[n * 3 + 2]; }
    out[n * 3 + 0] = r0; out[n * 3 + 1] = r1; out[n * 3 + 2] = r2;
}

// ---------------------------------------------------------------------------
// MFMA GEMM + fused BN-stats (r8 structure — best measured: 92 us @N1).
// B staged 16KB/phase in double-buffered LDS (2 k-subphases per barrier pair).
// ---------------------------------------------------------------------------
__global__ __launch_bounds__(256)
void gemm_mfma_cat(u16* __restrict__ O, const u16* __restrict__ A,
                   const u16* __restrict__ Bf, const float* __restrict__ bias,
                   float* __restrict__ partials)
{
    __shared__ u16 Bs[2][8192];               // 2 x 16KB
    const int tid  = threadIdx.x;
    const int wave = tid >> 6;
    const int lane = tid & 63;
    const int lrow = lane & 15;
    const int kg   = lane >> 4;
    const int r0   = blockIdx.x * 128 + wave * 32;

    const u16* A0 = A + (size_t)(r0 + lrow) * 768 + kg * 8;
    const u16* A1 = A0 + (size_t)16 * 768;

    f4v acc[2][8] = {};

    // prologue: stage phase 0 (16KB), load A for both subphases
#pragma unroll
    for (int i = 0; i < 4; ++i)
        *(s8v*)&Bs[0][i * 2048 + tid * 8] = *(const s8v*)(Bf + i * 2048 + tid * 8);
    s8v a00 = *(const s8v*)(A0);
    s8v a10 = *(const s8v*)(A1);
    s8v a01 = *(const s8v*)(A0 + 32);
    s8v a11 = *(const s8v*)(A1 + 32);
    __syncthreads();

#pragma unroll 1
    for (int p = 0; p < 12; ++p) {
        const int cur = p & 1, nxt = cur ^ 1;
        const u16* src = Bf + (p + 1) * 8192;
        s8v nb0 = *(const s8v*)(src + tid * 8);
        s8v nb1 = *(const s8v*)(src + 2048 + tid * 8);
        s8v nb2 = *(const s8v*)(src + 4096 + tid * 8);
        s8v nb3 = *(const s8v*)(src + 6144 + tid * 8);
        s8v na00 = *(const s8v*)(A0 + (p + 1) * 64);
        s8v na10 = *(const s8v*)(A1 + (p + 1) * 64);
        s8v na01 = *(const s8v*)(A0 + (p + 1) * 64 + 32);
        s8v na11 = *(const s8v*)(A1 + (p + 1) * 64 + 32);
        // subphase 0
#pragma unroll
        for (int ct = 0; ct < 8; ++ct) {
            s8v b = *(const s8v*)&Bs[cur][(ct * 64 + lane) * 8];
            acc[0][ct] = __builtin_amdgcn_mfma_f32_16x16x32_bf16(a00, b, acc[0][ct], 0, 0, 0);
            acc[1][ct] = __builtin_amdgcn_mfma_f32_16x16x32_bf16(a10, b, acc[1][ct], 0, 0, 0);
        }
        // subphase 1
#pragma unroll
        for (int ct = 0; ct < 8; ++ct) {
            s8v b = *(const s8v*)&Bs[cur][4096 + (ct * 64 + lane) * 8];
            acc[0][ct] = __builtin_amdgcn_mfma_f32_16x16x32_bf16(a01, b, acc[0][ct], 0, 0, 0);
            acc[1][ct] = __builtin_amdgcn_mfma_f32_16x16x32_bf16(a11, b, acc[1][ct], 0, 0, 0);
        }
        __syncthreads();                      // readers of Bs[nxt] done
        *(s8v*)&Bs[nxt][tid * 8]        = nb0;
        *(s8v*)&Bs[nxt][2048 + tid * 8] = nb1;
        *(s8v*)&Bs[nxt][4096 + tid * 8] = nb2;
        *(s8v*)&Bs[nxt][6144 + tid * 8] = nb3;
        __syncthreads();                      // Bs[nxt] published
        a00 = na00; a10 = na10; a01 = na01; a11 = na11;
    }

    __shared__ float sred[4][2][8][16];
    float cs[8], cq[8];
#pragma unroll
    for (int ct = 0; ct < 8; ++ct) { cs[ct] = 0.f; cq[ct] = 0.f; }

#pragma unroll
    for (int s = 0; s < 2; ++s)
#pragma unroll
        for (int ct = 0; ct < 8; ++ct) {
            int col = ct * 16 + lrow;
            float bv = bias[col];
#pragma unroll
            for (int j = 0; j < 4; ++j) {
                int row = r0 + s * 16 + kg * 4 + j;
                float v = acc[s][ct][j] + bv;
                O[(size_t)row * 128 + col] = f2b(v);
                cs[ct] += v; cq[ct] += v * v;
            }
        }
#pragma unroll
    for (int ct = 0; ct < 8; ++ct) {
        cs[ct] += __shfl_xor(cs[ct], 16); cs[ct] += __shfl_xor(cs[ct], 32);
        cq[ct] += __shfl_xor(cq[ct], 16); cq[ct] += __shfl_xor(cq[ct], 32);
    }
    if (lane < 16) {
#pragma unroll
        for (int ct = 0; ct < 8; ++ct) {
            sred[wave][0][ct][lane] = cs[ct];
            sred[wave][1][ct][lane] = cq[ct];
        }
    }
    __syncthreads();
    if (threadIdx.x < 128) {
        int ct = threadIdx.x >> 4, lr = threadIdx.x & 15;
        float S = 0.f, Q = 0.f;
#pragma unroll
        for (int w = 0; w < 4; ++w) { S += sred[w][0][ct][lr]; Q += sred[w][1][ct][lr]; }
        partials[blockIdx.x * 256 + threadIdx.x]       = S;
        partials[blockIdx.x * 256 + 128 + threadIdx.x] = Q;
    }
}

// all weight prep in one launch; blockIdx.y = 0..3 -> W2..W5, 4 -> W6
__global__ __launch_bounds__(256)
void wprep_all(const float* __restrict__ W2, const float* __restrict__ W3,
               const float* __restrict__ W4, const float* __restrict__ W5,
               const float* __restrict__ W6, u16* __restrict__ Bf,
               u16* __restrict__ W6t)
{
    int l = blockIdx.y;
    int idx = blockIdx.x * 256 + threadIdx.x;
    if (l == 4) {
        if (idx >= 16 * 768) return;
        int c = idx / 768, kk = idx % 768;
        int slot = kk >> 7, d = kk & 127;
        W6t[idx] = (c < 10) ? f2b(W6[(size_t)slot * 1280 + d * 10 + c]) : (u16)0;
        return;
    }
    const float* W = (l == 0) ? W2 : (l == 1) ? W3 : (l == 2) ? W4 : W5;
    int base = (l & 1) ? 5 : 0;
    int j    = idx & 7;
    int lane = (idx >> 3) & 63;
    int ct   = (idx >> 9) & 7;
    int k0s  = idx >> 12;
    int k    = k0s * 32 + (lane >> 4) * 8 + j;
    int col  = ct * 16 + (lane & 15);
    int slot = k >> 7, d = k & 127;
    int wk = slot - base; if (wk < 0) wk += 6;
    Bf[(size_t)l * LSTRIDE + idx] = f2b(W[(size_t)wk * 16384 + d * 128 + col]);
}

// layer-1 GEMM + fused stats. Block = 128 rows; T values staged in LDS.
__global__ __launch_bounds__(256)
void l1gemm(u16* __restrict__ O, const float* __restrict__ T0,
            const float* __restrict__ Tt, const float* __restrict__ W,
            const float* __restrict__ bias, float* __restrict__ partials)
{
    __shared__ float Ts[128][18];
    __shared__ float sh[2][128], sh2[2][128];
    int tid = threadIdx.x;
    int rbase = blockIdx.x * 128;
    for (int i = tid; i < 128 * 18; i += 256) {
        int r = i / 18, t = i % 18;
        int k = t / 3, j = t % 3;
        Ts[r][t] = (k == 0) ? T0[(size_t)(rbase + r) * 3 + j]
                            : Tt[(size_t)(k - 1) * N1 * 3 + (size_t)(rbase + r) * 3 + j];
    }
    __syncthreads();
    int c = tid & 127, h = tid >> 7;
    float w[18];
#pragma unroll
    for (int k = 0; k < 6; ++k)
#pragma unroll
        for (int j = 0; j < 3; ++j) w[k * 3 + j] = W[(size_t)k * 384 + j * 128 + c];
    float bv = bias[c];
    float S = 0.f, Q = 0.f;
    for (int i = 0; i < 64; ++i) {
        int r = h * 64 + i;
        float acc = bv;
#pragma unroll
        for (int t = 0; t < 18; ++t) acc += Ts[r][t] * w[t];
        O[(size_t)(rbase + r) * 128 + c] = f2b(acc);
        S += acc; Q += acc * acc;
    }
    sh[h][c] = S; sh2[h][c] = Q;
    __syncthreads();
    if (tid < 128) {
        partials[blockIdx.x * 256 + tid]       = sh[0][tid] + sh[1][tid];
        partials[blockIdx.x * 256 + 128 + tid] = sh2[0][tid] + sh2[1][tid];
    }
}

// layer-6 GEMM + bias + relu
__global__ __launch_bounds__(256)
void out10_cat(float* __restrict__ O10, const u16* __restrict__ cat,
               const u16* __restrict__ W6t, const float* __restrict__ bias)
{
    int col = threadIdx.x & 15;
    int row = blockIdx.x * 16 + (threadIdx.x >> 4);
    const u16* a = cat + (size_t)row * 768;
    const u16* w = W6t + (size_t)col * 768;
    float acc = 0.f;
#pragma unroll 4
    for (int k0 = 0; k0 < 768; k0 += 8) {
        s8v av = *(const s8v*)(a + k0);
        s8v wv = *(const s8v*)(w + k0);
#pragma unroll
        for (int j = 0; j < 8; ++j)
            acc += b2f((u16)av[j]) * b2f((u16)wv[j]);
    }
    if (col < 10)
        O10[(size_t)row * 10 + col] = fmaxf(acc + bias[col], 0.f);
}

// ---------------------------------------------------------------------------
// Fused BN reduce: 64 blocks; stage-1 strided sums -> part2; last block
// (elected via atomic counter; deterministic output) finalizes gsc/gso.
// ---------------------------------------------------------------------------
__global__ __launch_bounds__(256)
void bn_reduce_f(const float* __restrict__ partials, int nblk, int N,
                 const float* __restrict__ g, const float* __restrict__ bt,
                 float* __restrict__ gsc, float* __restrict__ gso,
                 float* __restrict__ part2, unsigned* __restrict__ cnt)
{
    int tid = threadIdx.x;
    float S = 0.f;
#pragma unroll 4
    for (int b = blockIdx.x; b < nblk; b += 64)
        S += partials[(size_t)b * 256 + tid];
    part2[blockIdx.x * 256 + tid] = S;
    __threadfence();
    __syncthreads();
    __shared__ int last;
    if (tid == 0) last = (atomicAdd(cnt, 1u) == 63u) ? 1 : 0;
    __syncthreads();
    if (!last) return;
    __threadfence();
    int c = tid & 127, h = tid >> 7;
    float Sa = 0.f, Qa = 0.f;
#pragma unroll 8
    for (int b = h; b < 64; b += 2) {
        Sa += part2[b * 256 + c];
        Qa += part2[b * 256 + 128 + c];
    }
    __shared__ float shS[2][128], shQ[2][128];
    shS[h][c] = Sa; shQ[h][c] = Qa;
    __syncthreads();
    if (tid < 128) {
        float Sx = shS[0][tid] + shS[1][tid];
        float Qx = shQ[0][tid] + shQ[1][tid];
        float inv_n = 1.f / (float)N;
        float mu = Sx * inv_n;
        float var = Qx * inv_n - mu * mu;
        float is = rsqrtf(var + 1e-5f);
        float sc = is * g[tid];
        gsc[tid] = sc;
        gso[tid] = bt[tid] - mu * sc;
    }
    if (tid == 0) *cnt = 0u;
}

// BN + relu + 2x2 max-pool fused (8 channels/thread) using gsc/gso
__global__ __launch_bounds__(256)
void bn_apply_pool8(const u16* __restrict__ O, u16* __restrict__ cat, int outSlot,
                    int s, int Nout,
                    const float* __restrict__ gsc, const float* __restrict__ gso)
{
    int idx = blockIdx.x * 256 + threadIdx.x;    // over Nout*16
    if (idx >= Nout * 16) return;
    int c8 = idx & 15;
    int n2 = idx >> 4;
    int h  = s >> 1;
    int x2 = n2 % h;
    int y2 = (n2 / h) % h;
    int gg = n2 / (h * h);
    int base = (gg * s + 2 * y2) * s + 2 * x2;
    s8v v0 = *(const s8v*)(O + (size_t)base * 128 + c8 * 8);
    s8v v1 = *(const s8v*)(O + (size_t)(base + 1) * 128 + c8 * 8);
    s8v v2 = *(const s8v*)(O + (size_t)(base + s) * 128 + c8 * 8);
    s8v v3 = *(const s8v*)(O + (size_t)(base + s + 1) * 128 + c8 * 8);
    s8v ov;
#pragma unroll
    for (int j = 0; j < 8; ++j) {
        int c = c8 * 8 + j;
        float sc = gsc[c], so = gso[c];
        float m =          b2f((u16)v0[j]) * sc + so;
        m = fmaxf(m, b2f((u16)v1[j]) * sc + so);
        m = fmaxf(m, b2f((u16)v2[j]) * sc + so);
        m = fmaxf(m, b2f((u16)v3[j]) * sc + so);
        ov[j] = (short)f2b(fmaxf(m, 0.f));
    }
    *(s8v*)(cat + (size_t)n2 * 768 + outSlot * 128 + c8 * 8) = ov;
}

// fused tail: pool3(16->8) + orientation pool + global max + log_softmax
__global__ __launch_bounds__(512)
void tail_fused(const float* __restrict__ O10, float* __restrict__ out)
{
    __shared__ float p4[512][10];
    __shared__ float G[8][10];
    __shared__ float rowm[8], rowl[8];
    int t = threadIdx.x;
    for (int i = t; i < 5120; i += 512) {
        int c = i % 10, n = i / 10;
        int x = n & 7, y = (n >> 3) & 7, b = n >> 6;
        float m = -INFINITY;
        for (int o = 0; o < L_OR; ++o) {
            int base = ((b * L_OR + o) * 16 + 2 * y) * 16 + 2 * x;
            m = fmaxf(m, O10[(size_t)base * 10 + c]);
            m = fmaxf(m, O10[(size_t)(base + 1) * 10 + c]);
            m = fmaxf(m, O10[(size_t)(base + 16) * 10 + c]);
            m = fmaxf(m, O10[(size_t)(base + 17) * 10 + c]);
        }
        p4[n][c] = m;
    }
    __syncthreads();
    if (t < 80) {
        int b = t / 10, c = t % 10;
        float m = -INFINITY;
        for (int p = 0; p < 64; ++p) m = fmaxf(m, p4[b * 64 + p][c]);
        G[b][c] = m;
    }
    __syncthreads();
    if (t < 8) {
        float m = -INFINITY;
        for (int c = 0; c < 10; ++c) m = fmaxf(m, G[t][c]);
        float s = 0.f;
        for (int c = 0; c < 10; ++c) s += expf(G[t][c] - m);
        rowm[t] = m; rowl[t] = logf(s);
    }
    __syncthreads();
    if (t < 80) {
        int b = t / 10, c = t % 10;
        out[t] = G[b][c] - rowm[b] - rowl[b];
    }
}

// ---------------------------------------------------------------------------
// Host-side orchestration
// ---------------------------------------------------------------------------
static void launch_lapb(u16* cat, int os, int is, int ts, const float* wtab,
                        int S, int N, float alpha, hipStream_t st)
{
    dim3 grid(N / 16), block(256);
    if (S == 64)      hipLaunchKernelGGL(lap128b<64>, grid, block, 0, st, cat, os, is, ts, wtab, alpha);
    else if (S == 32) hipLaunchKernelGGL(lap128b<32>, grid, block, 0, st, cat, os, is, ts, wtab, alpha);
    else              hipLaunchKernelGGL(lap128b<16>, grid, block, 0, st, cat, os, is, ts, wtab, alpha);
}

static void cheb_laps_b5(u16* cat, const float* wtab, int S, int N, hipStream_t st)
{
    for (int k = 1; k < 6; ++k) {
        int os = (k + 5) % 6;
        int is = (k - 1 + 5) % 6;
        int ts = (k >= 2) ? (k - 2 + 5) % 6 : -1;
        launch_lapb(cat, os, is, ts, wtab, S, N, (k == 1) ? 1.f : 2.f, st);
    }
}

static void cheb_laps_2to5(u16* cat, const float* wtab, int S, int N, hipStream_t st)
{
    for (int k = 2; k < 6; ++k)
        launch_lapb(cat, k, k - 1, k - 2, wtab, S, N, 2.f, st);
}

static void launch_lap1bn(u16* cat, const u16* O, const float* wtab,
                          const float* gsc, const float* gso,
                          int S, int N, hipStream_t st)
{
    dim3 grid(N / 16), block(256);
    if (S == 64)      hipLaunchKernelGGL(lap1bn<64>, grid, block, 0, st, cat, O, 0, 1, wtab, gsc, gso);
    else if (S == 32) hipLaunchKernelGGL(lap1bn<32>, grid, block, 0, st, cat, O, 0, 1, wtab, gsc, gso);
    else              hipLaunchKernelGGL(lap1bn<16>, grid, block, 0, st, cat, O, 0, 1, wtab, gsc, gso);
}

extern "C" void kernel_launch(void* const* d_in, const int* in_sizes, int n_in,
                              void* d_out, int out_size, void* d_ws, size_t ws_size,
                              hipStream_t stream)
{
    const float* x   = (const float*)d_in[0];
    const float* ea1 = (const float*)d_in[2];
    const float* ea2 = (const float*)d_in[4];
    const float* ea3 = (const float*)d_in[6];
    const float* W1  = (const float*)d_in[12];
    const float* b1  = (const float*)d_in[13];
    const float* W2  = (const float*)d_in[14];
    const float* b2  = (const float*)d_in[15];
    const float* W3  = (const float*)d_in[16];
    const float* b3  = (const float*)d_in[17];
    const float* W4  = (const float*)d_in[18];
    const float* b4  = (const float*)d_in[19];
    const float* W5  = (const float*)d_in[20];
    const float* b5  = (const float*)d_in[21];
    const float* W6  = (const float*)d_in[22];
    const float* b6  = (const float*)d_in[23];
    const float* g1  = (const float*)d_in[24];
    const float* be1 = (const float*)d_in[25];
    const float* g2  = (const float*)d_in[26];
    const float* be2 = (const float*)d_in[27];
    const float* g3  = (const float*)d_in[28];
    const float* be3 = (const float*)d_in[29];
    const float* g4  = (const float*)d_in[30];
    const float* be4 = (const float*)d_in[31];
    const float* g5  = (const float*)d_in[32];
    const float* be5 = (const float*)d_in[33];

    u16 *cat, *O, *Bt, *W6t;
    float *Tt, *O10, *part, *part2, *gsc, *gso, *wt1, *wt2, *wt3;
    unsigned* cnt;
    if (hipGetSymbolAddress((void**)&cat, HIP_SYMBOL(g_cat)) != hipSuccess) return;
    if (hipGetSymbolAddress((void**)&O,   HIP_SYMBOL(g_O))   != hipSuccess) return;
    if (hipGetSymbolAddress((void**)&Tt,  HIP_SYMBOL(g_Tt))  != hipSuccess) return;
    if (hipGetSymbolAddress((void**)&Bt,  HIP_SYMBOL(g_Bt))  != hipSuccess) return;
    if (hipGetSymbolAddress((void**)&W6t, HIP_SYMBOL(g_W6t)) != hipSuccess) return;
    if (hipGetSymbolAddress((void**)&O10, HIP_SYMBOL(g_O10)) != hipSuccess) return;
    if (hipGetSymbolAddress((void**)&part,  HIP_SYMBOL(g_part))  != hipSuccess) return;
    if (hipGetSymbolAddress((void**)&part2, HIP_SYMBOL(g_part2)) != hipSuccess) return;
    if (hipGetSymbolAddress((void**)&gsc, HIP_SYMBOL(g_gsc)) != hipSuccess) return;
    if (hipGetSymbolAddress((void**)&gso, HIP_SYMBOL(g_gso)) != hipSuccess) return;
    if (hipGetSymbolAddress((void**)&wt1, HIP_SYMBOL(g_wt1)) != hipSuccess) return;
    if (hipGetSymbolAddress((void**)&wt2, HIP_SYMBOL(g_wt2)) != hipSuccess) return;
    if (hipGetSymbolAddress((void**)&wt3, HIP_SYMBOL(g_wt3)) != hipSuccess) return;
    if (hipGetSymbolAddress((void**)&cnt, HIP_SYMBOL(g_cnt)) != hipSuccess) return;

    dim3 blk(256);

    // ---------- prep ----------
    hipLaunchKernelGGL(eaprep_all, dim3((N1 + N2 + N3) / 256), blk, 0, stream,
                       wt1, wt2, wt3, ea1, ea2, ea3);
    hipLaunchKernelGGL(wprep_all, dim3(384, 5), blk, 0, stream, W2, W3, W4, W5, W6, Bt, W6t);

    // ---------- Layer 1: cheb(x[N1,3], W1) -> O bf16 (+stats) ----------
    {
        float* t1 = Tt;
        float* t2 = Tt + (size_t)N1 * 3;
        float* t3 = Tt + (size_t)2 * N1 * 3;
        float* t4 = Tt + (size_t)3 * N1 * 3;
        float* t5 = Tt + (size_t)4 * N1 * 3;
        dim3 gl((N1 + 255) / 256);
        hipLaunchKernelGGL(lap3_kernel<64>, gl, blk, 0, stream, t1, x,  (const float*)nullptr, wt1, 1.f);
        hipLaunchKernelGGL(lap3_kernel<64>, gl, blk, 0, stream, t2, t1, x,  wt1, 2.f);
        hipLaunchKernelGGL(lap3_kernel<64>, gl, blk, 0, stream, t3, t2, t1, wt1, 2.f);
        hipLaunchKernelGGL(lap3_kernel<64>, gl, blk, 0, stream, t4, t3, t2, wt1, 2.f);
        hipLaunchKernelGGL(lap3_kernel<64>, gl, blk, 0, stream, t5, t4, t3, wt1, 2.f);
        hipLaunchKernelGGL(l1gemm, dim3(N1 / 128), blk, 0, stream, O, x, Tt, W1, b1, part);
    }
    hipLaunchKernelGGL(bn_reduce_f, dim3(64), blk, 0, stream, part, N1 / 128, N1,
                       g1, be1, gsc, gso, part2, cnt);

    // ---------- Layer 2 (N1): fused BN-lap, laps, GEMM ----------
    launch_lap1bn(cat, O, wt1, gsc, gso, 64, N1, stream);
    cheb_laps_2to5(cat, wt1, 64, N1, stream);
    hipLaunchKernelGGL(gemm_mfma_cat, dim3(N1 / 128), blk, 0, stream, O, cat, Bt, b2, part);
    hipLaunchKernelGGL(bn_reduce_f, dim3(64), blk, 0, stream, part, N1 / 128, N1,
                       g2, be2, gsc, gso, part2, cnt);
    hipLaunchKernelGGL(bn_apply_pool8, dim3(N2 / 16), blk, 0, stream,
                       O, cat, 5, 64, N2, gsc, gso);

    // ---------- Layer 3 (N2, base 5) ----------
    cheb_laps_b5(cat, wt2, 32, N2, stream);
    hipLaunchKernelGGL(gemm_mfma_cat, dim3(N2 / 128), blk, 0, stream, O, cat, Bt + 1 * LSTRIDE, b3, part);
    hipLaunchKernelGGL(bn_reduce_f, dim3(64), blk, 0, stream, part, N2 / 128, N2,
                       g3, be3, gsc, gso, part2, cnt);

    // ---------- Layer 4 (N2, base 0) ----------
    launch_lap1bn(cat, O, wt2, gsc, gso, 32, N2, stream);
    cheb_laps_2to5(cat, wt2, 32, N2, stream);
    hipLaunchKernelGGL(gemm_mfma_cat, dim3(N2 / 128), blk, 0, stream, O, cat, Bt + 2 * LSTRIDE, b4, part);
    hipLaunchKernelGGL(bn_reduce_f, dim3(64), blk, 0, stream, part, N2 / 128, N2,
                       g4, be4, gsc, gso, part2, cnt);
    hipLaunchKernelGGL(bn_apply_pool8, dim3(N3 / 16), blk, 0, stream,
                       O, cat, 5, 32, N3, gsc, gso);

    // ---------- Layer 5 (N3, base 5) ----------
    cheb_laps_b5(cat, wt3, 16, N3, stream);
    hipLaunchKernelGGL(gemm_mfma_cat, dim3(N3 / 128), blk, 0, stream, O, cat, Bt + 3 * LSTRIDE, b5, part);
    hipLaunchKernelGGL(bn_reduce_f, dim3(64), blk, 0, stream, part, N3 / 128, N3,
                       g5, be5, gsc, gso, part2, cnt);

    // ---------- Layer 6 (N3, base 0, out 10, relu fused) ----------
    launch_lap1bn(cat, O, wt3, gsc, gso, 16, N3, stream);
    cheb_laps_2to5(cat, wt3, 16, N3, stream);
    hipLaunchKernelGGL(out10_cat, dim3(N3 / 16), blk, 0, stream, O10, cat, W6t, b6);

    // ---------- fused tail ----------
    hipLaunchKernelGGL(tail_fused, dim3(1), dim3(512), 0, stream, O10, (float*)d_out);
}